// Round 1
// baseline (6784.898 us; speedup 1.0000x reference)
//
#include <hip/hip_runtime.h>
#include <hip/hip_bf16.h>

// 3-layer GCN: per layer  out = relu(segment_sum(h[src] -> dst) @ W + b)
// Restructured as aggregate-first (scatter commutes with linear transform):
//   a = scatter(h); out = relu(a @ W + b)   [fused bias+relu GEMM epilogue]

typedef short bf16x8 __attribute__((ext_vector_type(8)));
typedef float f32x4 __attribute__((ext_vector_type(4)));

__device__ __forceinline__ short f2bf(float f) {
    __hip_bfloat16 b = __float2bfloat16(f);
    return *reinterpret_cast<short*>(&b);
}

// W [K][256] f32  ->  Wt [256][K] bf16 (transposed for LDS row-major staging)
__global__ void wconvert(const float* __restrict__ W, short* __restrict__ Wt, int K) {
    int idx = blockIdx.x * blockDim.x + threadIdx.x;
    if (idx >= K * 256) return;
    int n = idx / K, k = idx - n * K;
    Wt[idx] = f2bf(W[k * 256 + n]);
}

// COO scatter-add: agg[dst[e]] += h[src[e]], float4 per thread.
__global__ void scatter_add(const float4* __restrict__ h, float* __restrict__ agg,
                            const int* __restrict__ ei, int E, int lf4) {
    int idx = blockIdx.x * blockDim.x + threadIdx.x;
    int e = idx >> lf4;
    if (e >= E) return;
    int F4 = 1 << lf4;
    int f = idx & (F4 - 1);
    int s = ei[e];
    int d = ei[E + e];
    float4 v = h[(size_t)s * F4 + f];
    float* o = agg + (((size_t)d * F4 + f) << 2);
    atomicAdd(o + 0, v.x);
    atomicAdd(o + 1, v.y);
    atomicAdd(o + 2, v.z);
    atomicAdd(o + 3, v.w);
}

// C[M,256] = relu(A[M,K] @ W[K,256] + bias)   A f32 (cvt to bf16 in staging),
// W given transposed bf16 Wt[256][K]. 128x128 tile, 4 waves (2x2), 16x16x32 MFMA.
__launch_bounds__(256)
__global__ void gemm_bias_relu(const float* __restrict__ A, const short* __restrict__ Wt,
                               const float* __restrict__ bias, float* __restrict__ out,
                               int M, int K) {
    __shared__ short As[128][72];  // +8 pad: 144B row stride -> 2-way max conflict
    __shared__ short Bs[128][72];

    const int tid = threadIdx.x;
    const int lane = tid & 63, wid = tid >> 6;
    const int wr = wid >> 1, wc = wid & 1;     // wave 2x2 -> 64x64 each
    const int lr = lane & 15, lg = lane >> 4;
    const int m0 = blockIdx.x * 128;
    const int n0 = blockIdx.y * 128;

    f32x4 acc[4][4];
#pragma unroll
    for (int i = 0; i < 4; ++i)
#pragma unroll
        for (int j = 0; j < 4; ++j)
#pragma unroll
            for (int r = 0; r < 4; ++r) acc[i][j][r] = 0.0f;

    const int srow = tid >> 2;          // 0..63
    const int scol = (tid & 3) << 4;    // 0,16,32,48

    for (int k0 = 0; k0 < K; k0 += 64) {
        __syncthreads();
        // stage A (f32 -> bf16) and Bt (bf16 copy): 2 passes of 64 rows
#pragma unroll
        for (int pass = 0; pass < 2; ++pass) {
            int row = pass * 64 + srow;
            int gm = m0 + row;
            short tmp[16];
            if (gm < M) {
                const float4* ap = reinterpret_cast<const float4*>(A + (size_t)gm * K + k0 + scol);
#pragma unroll
                for (int q = 0; q < 4; ++q) {
                    float4 v = ap[q];
                    tmp[q * 4 + 0] = f2bf(v.x);
                    tmp[q * 4 + 1] = f2bf(v.y);
                    tmp[q * 4 + 2] = f2bf(v.z);
                    tmp[q * 4 + 3] = f2bf(v.w);
                }
            } else {
#pragma unroll
                for (int q = 0; q < 16; ++q) tmp[q] = 0;
            }
            *reinterpret_cast<uint4*>(&As[row][scol])     = *reinterpret_cast<uint4*>(&tmp[0]);
            *reinterpret_cast<uint4*>(&As[row][scol + 8]) = *reinterpret_cast<uint4*>(&tmp[8]);

            const uint4* bp = reinterpret_cast<const uint4*>(Wt + (size_t)(n0 + row) * K + k0 + scol);
            *reinterpret_cast<uint4*>(&Bs[row][scol])     = bp[0];
            *reinterpret_cast<uint4*>(&Bs[row][scol + 8]) = bp[1];
        }
        __syncthreads();

#pragma unroll
        for (int ksub = 0; ksub < 2; ++ksub) {
            const int kb = ksub * 32 + 4 * lg;
            bf16x8 a[4], b[4];
#pragma unroll
            for (int mi = 0; mi < 4; ++mi) {
                int row = wr * 64 + mi * 16 + lr;
                uint2* pa = reinterpret_cast<uint2*>(&a[mi]);
                pa[0] = *reinterpret_cast<const uint2*>(&As[row][kb]);
                pa[1] = *reinterpret_cast<const uint2*>(&As[row][kb + 16]);
            }
#pragma unroll
            for (int ni = 0; ni < 4; ++ni) {
                int row = wc * 64 + ni * 16 + lr;
                uint2* pb = reinterpret_cast<uint2*>(&b[ni]);
                pb[0] = *reinterpret_cast<const uint2*>(&Bs[row][kb]);
                pb[1] = *reinterpret_cast<const uint2*>(&Bs[row][kb + 16]);
            }
#pragma unroll
            for (int mi = 0; mi < 4; ++mi)
#pragma unroll
                for (int ni = 0; ni < 4; ++ni)
                    acc[mi][ni] = __builtin_amdgcn_mfma_f32_16x16x32_bf16(a[mi], b[ni], acc[mi][ni], 0, 0, 0);
        }
    }

    // epilogue: bias + relu, f32 store. D layout: row = 4*lg + r, col = lr (per 16x16 frag)
    float bv[4];
#pragma unroll
    for (int ni = 0; ni < 4; ++ni) bv[ni] = bias[n0 + wc * 64 + ni * 16 + lr];
#pragma unroll
    for (int mi = 0; mi < 4; ++mi) {
        int gmBase = m0 + wr * 64 + mi * 16 + 4 * lg;
#pragma unroll
        for (int r = 0; r < 4; ++r) {
            int gm = gmBase + r;
            if (gm >= M) continue;
#pragma unroll
            for (int ni = 0; ni < 4; ++ni) {
                int gn = n0 + wc * 64 + ni * 16 + lr;
                float v = acc[mi][ni][r] + bv[ni];
                out[(size_t)gm * 256 + gn] = v > 0.0f ? v : 0.0f;
            }
        }
    }
}

extern "C" void kernel_launch(void* const* d_in, const int* in_sizes, int n_in,
                              void* d_out, int out_size, void* d_ws, size_t ws_size,
                              hipStream_t stream) {
    const float* x  = (const float*)d_in[0];
    const int*   ei = (const int*)d_in[1];
    const float* W1 = (const float*)d_in[2];
    const float* b1 = (const float*)d_in[3];
    const float* W2 = (const float*)d_in[4];
    const float* b2 = (const float*)d_in[5];
    const float* W3 = (const float*)d_in[6];
    const float* b3 = (const float*)d_in[7];
    float* out = (float*)d_out;

    const int Nn = 50000, E = 800000, F0 = 128, F = 256;

    char* ws = (char*)d_ws;
    float* agg = (float*)ws;                              // 50000*256 f32 = 51.2 MB
    short* Wt1 = (short*)(ws + (size_t)Nn * F * 4);       // 128*256 bf16
    short* Wt2 = Wt1 + F0 * F;                            // 256*256 bf16
    short* Wt3 = Wt2 + F * F;

    // weights -> transposed bf16 (once per launch)
    wconvert<<<(F0 * F + 255) / 256, 256, 0, stream>>>(W1, Wt1, F0);
    wconvert<<<(F * F + 255) / 256, 256, 0, stream>>>(W2, Wt2, F);
    wconvert<<<(F * F + 255) / 256, 256, 0, stream>>>(W3, Wt3, F);

    const dim3 gemmGrid((Nn + 127) / 128, 2);

    // ---- layer 1: agg = scatter(x) [F0=128]; out = relu(agg @ W1 + b1)
    hipMemsetAsync(agg, 0, (size_t)Nn * F0 * 4, stream);
    {
        int total = E << 5;  // E * (128/4)
        scatter_add<<<(total + 255) / 256, 256, 0, stream>>>((const float4*)x, agg, ei, E, 5);
    }
    gemm_bias_relu<<<gemmGrid, 256, 0, stream>>>(agg, Wt1, b1, out, Nn, F0);

    // ---- layer 2
    hipMemsetAsync(agg, 0, (size_t)Nn * F * 4, stream);
    {
        int total = E << 6;  // E * (256/4)
        scatter_add<<<(total + 255) / 256, 256, 0, stream>>>((const float4*)out, agg, ei, E, 6);
    }
    gemm_bias_relu<<<gemmGrid, 256, 0, stream>>>(agg, Wt2, b2, out, Nn, F);

    // ---- layer 3
    hipMemsetAsync(agg, 0, (size_t)Nn * F * 4, stream);
    {
        int total = E << 6;
        scatter_add<<<(total + 255) / 256, 256, 0, stream>>>((const float4*)out, agg, ei, E, 6);
    }
    gemm_bias_relu<<<gemmGrid, 256, 0, stream>>>(agg, Wt3, b3, out, Nn, F);
}

// Round 2
// 596.855 us; speedup vs baseline: 11.3677x; 11.3677x over previous
//
#include <hip/hip_runtime.h>
#include <hip/hip_bf16.h>

// 3-layer GCN: per layer  out = relu(segment_sum(h[src] -> dst) @ W + b)
// Aggregate-first (scatter commutes with the linear transform), and the
// aggregation is a CSR GATHER (no atomics): CSR of incoming edges is built
// once per launch and reused by all 3 layers.

typedef short bf16x8 __attribute__((ext_vector_type(8)));
typedef float f32x4 __attribute__((ext_vector_type(4)));

__device__ __forceinline__ short f2bf(float f) {
    __hip_bfloat16 b = __float2bfloat16(f);
    return *reinterpret_cast<short*>(&b);
}

// W [K][256] f32  ->  Wt [256][K] bf16 (transposed for LDS row-major staging)
__global__ void wconvert(const float* __restrict__ W, short* __restrict__ Wt, int K) {
    int idx = blockIdx.x * blockDim.x + threadIdx.x;
    if (idx >= K * 256) return;
    int n = idx / K, k = idx - n * K;
    Wt[idx] = f2bf(W[k * 256 + n]);
}

// ---------------- CSR build (once per launch, reused 3x) ----------------

__global__ void hist_dst(const int* __restrict__ ei, int* __restrict__ deg, int E) {
    int e = blockIdx.x * blockDim.x + threadIdx.x;
    if (e < E) atomicAdd(&deg[ei[E + e]], 1);
}

// single-block exclusive scan over n degrees -> off (and a second copy: cursor)
__global__ void exscan(const int* __restrict__ deg, int* __restrict__ off,
                       int* __restrict__ cursor, int n) {
    __shared__ int part[1024];
    const int tid = threadIdx.x;
    const int chunk = (n + 1023) >> 10;
    const int s = tid * chunk;
    const int e = min(s + chunk, n);
    int sum = 0;
    for (int i = s; i < e; ++i) sum += deg[i];
    part[tid] = sum;
    __syncthreads();
    for (int d = 1; d < 1024; d <<= 1) {
        int v = (tid >= d) ? part[tid - d] : 0;
        __syncthreads();
        part[tid] += v;
        __syncthreads();
    }
    int base = (tid == 0) ? 0 : part[tid - 1];
    for (int i = s; i < e; ++i) {
        off[i] = base;
        cursor[i] = base;
        base += deg[i];
    }
}

__global__ void fill_csr(const int* __restrict__ ei, int* __restrict__ cursor,
                         int* __restrict__ csr, int E) {
    int e = blockIdx.x * blockDim.x + threadIdx.x;
    if (e < E) {
        int pos = atomicAdd(&cursor[ei[E + e]], 1);
        csr[pos] = ei[e];  // src
    }
}

// ---------------- CSR gather: one wave per node, lane owns VEC floats -----

template <int VEC>
__global__ void gather_csr(const float* __restrict__ h, float* __restrict__ agg,
                           const int* __restrict__ off, const int* __restrict__ deg,
                           const int* __restrict__ csr, int N) {
    typedef float fvec __attribute__((ext_vector_type(VEC)));
    const int gw = (blockIdx.x * blockDim.x + threadIdx.x) >> 6;  // node id
    if (gw >= N) return;
    const int lane = threadIdx.x & 63;
    const int col = lane * VEC;
    const int F = 64 * VEC;
    const int base = off[gw];
    const int d = deg[gw];

    fvec acc;
#pragma unroll
    for (int q = 0; q < VEC; ++q) acc[q] = 0.0f;

    int j = 0;
    for (; j + 4 <= d; j += 4) {
        int s0 = csr[base + j], s1 = csr[base + j + 1];
        int s2 = csr[base + j + 2], s3 = csr[base + j + 3];
        fvec v0 = *reinterpret_cast<const fvec*>(h + (size_t)s0 * F + col);
        fvec v1 = *reinterpret_cast<const fvec*>(h + (size_t)s1 * F + col);
        fvec v2 = *reinterpret_cast<const fvec*>(h + (size_t)s2 * F + col);
        fvec v3 = *reinterpret_cast<const fvec*>(h + (size_t)s3 * F + col);
        acc += v0 + v1 + v2 + v3;
    }
    for (; j < d; ++j) {
        int s = csr[base + j];
        acc += *reinterpret_cast<const fvec*>(h + (size_t)s * F + col);
    }
    *reinterpret_cast<fvec*>(agg + (size_t)gw * F + col) = acc;
}

// ---------------- GEMM: C[M,256] = relu(A[M,K] @ W[K,256] + bias) ---------
// A f32 (cvt to bf16 in staging), W transposed bf16 Wt[256][K].
// 128x128 tile, 4 waves (2x2), 16x16x32 MFMA.
__launch_bounds__(256)
__global__ void gemm_bias_relu(const float* __restrict__ A, const short* __restrict__ Wt,
                               const float* __restrict__ bias, float* __restrict__ out,
                               int M, int K) {
    __shared__ short As[128][72];  // +8 pad
    __shared__ short Bs[128][72];

    const int tid = threadIdx.x;
    const int lane = tid & 63, wid = tid >> 6;
    const int wr = wid >> 1, wc = wid & 1;
    const int lr = lane & 15, lg = lane >> 4;
    const int m0 = blockIdx.x * 128;
    const int n0 = blockIdx.y * 128;

    f32x4 acc[4][4];
#pragma unroll
    for (int i = 0; i < 4; ++i)
#pragma unroll
        for (int j = 0; j < 4; ++j)
#pragma unroll
            for (int r = 0; r < 4; ++r) acc[i][j][r] = 0.0f;

    const int srow = tid >> 2;
    const int scol = (tid & 3) << 4;

    for (int k0 = 0; k0 < K; k0 += 64) {
        __syncthreads();
#pragma unroll
        for (int pass = 0; pass < 2; ++pass) {
            int row = pass * 64 + srow;
            int gm = m0 + row;
            short tmp[16];
            if (gm < M) {
                const float4* ap = reinterpret_cast<const float4*>(A + (size_t)gm * K + k0 + scol);
#pragma unroll
                for (int q = 0; q < 4; ++q) {
                    float4 v = ap[q];
                    tmp[q * 4 + 0] = f2bf(v.x);
                    tmp[q * 4 + 1] = f2bf(v.y);
                    tmp[q * 4 + 2] = f2bf(v.z);
                    tmp[q * 4 + 3] = f2bf(v.w);
                }
            } else {
#pragma unroll
                for (int q = 0; q < 16; ++q) tmp[q] = 0;
            }
            *reinterpret_cast<uint4*>(&As[row][scol])     = *reinterpret_cast<uint4*>(&tmp[0]);
            *reinterpret_cast<uint4*>(&As[row][scol + 8]) = *reinterpret_cast<uint4*>(&tmp[8]);

            const uint4* bp = reinterpret_cast<const uint4*>(Wt + (size_t)(n0 + row) * K + k0 + scol);
            *reinterpret_cast<uint4*>(&Bs[row][scol])     = bp[0];
            *reinterpret_cast<uint4*>(&Bs[row][scol + 8]) = bp[1];
        }
        __syncthreads();

#pragma unroll
        for (int ksub = 0; ksub < 2; ++ksub) {
            const int kb = ksub * 32 + 4 * lg;
            bf16x8 a[4], b[4];
#pragma unroll
            for (int mi = 0; mi < 4; ++mi) {
                int row = wr * 64 + mi * 16 + lr;
                uint2* pa = reinterpret_cast<uint2*>(&a[mi]);
                pa[0] = *reinterpret_cast<const uint2*>(&As[row][kb]);
                pa[1] = *reinterpret_cast<const uint2*>(&As[row][kb + 16]);
            }
#pragma unroll
            for (int ni = 0; ni < 4; ++ni) {
                int row = wc * 64 + ni * 16 + lr;
                uint2* pb = reinterpret_cast<uint2*>(&b[ni]);
                pb[0] = *reinterpret_cast<const uint2*>(&Bs[row][kb]);
                pb[1] = *reinterpret_cast<const uint2*>(&Bs[row][kb + 16]);
            }
#pragma unroll
            for (int mi = 0; mi < 4; ++mi)
#pragma unroll
                for (int ni = 0; ni < 4; ++ni)
                    acc[mi][ni] = __builtin_amdgcn_mfma_f32_16x16x32_bf16(a[mi], b[ni], acc[mi][ni], 0, 0, 0);
        }
    }

    float bv[4];
#pragma unroll
    for (int ni = 0; ni < 4; ++ni) bv[ni] = bias[n0 + wc * 64 + ni * 16 + lr];
#pragma unroll
    for (int mi = 0; mi < 4; ++mi) {
        int gmBase = m0 + wr * 64 + mi * 16 + 4 * lg;
#pragma unroll
        for (int r = 0; r < 4; ++r) {
            int gm = gmBase + r;
            if (gm >= M) continue;
#pragma unroll
            for (int ni = 0; ni < 4; ++ni) {
                int gn = n0 + wc * 64 + ni * 16 + lr;
                float v = acc[mi][ni][r] + bv[ni];
                out[(size_t)gm * 256 + gn] = v > 0.0f ? v : 0.0f;
            }
        }
    }
}

extern "C" void kernel_launch(void* const* d_in, const int* in_sizes, int n_in,
                              void* d_out, int out_size, void* d_ws, size_t ws_size,
                              hipStream_t stream) {
    const float* x  = (const float*)d_in[0];
    const int*   ei = (const int*)d_in[1];
    const float* W1 = (const float*)d_in[2];
    const float* b1 = (const float*)d_in[3];
    const float* W2 = (const float*)d_in[4];
    const float* b2 = (const float*)d_in[5];
    const float* W3 = (const float*)d_in[6];
    const float* b3 = (const float*)d_in[7];
    float* out = (float*)d_out;

    const int Nn = 50000, E = 800000, F0 = 128, F = 256;

    char* ws = (char*)d_ws;
    float* agg = (float*)ws;                                  // 51.2 MB
    short* Wt1 = (short*)(ws + (size_t)Nn * F * 4);
    short* Wt2 = Wt1 + F0 * F;
    short* Wt3 = Wt2 + F * F;
    char*  ip  = (char*)(Wt3 + F * F);
    int* deg    = (int*)ip;                                   // 200 KB
    int* off    = deg + Nn;
    int* cursor = off + Nn;
    int* csr    = cursor + Nn;                                // 3.2 MB

    // weights -> transposed bf16
    wconvert<<<(F0 * F + 255) / 256, 256, 0, stream>>>(W1, Wt1, F0);
    wconvert<<<(F * F + 255) / 256, 256, 0, stream>>>(W2, Wt2, F);
    wconvert<<<(F * F + 255) / 256, 256, 0, stream>>>(W3, Wt3, F);

    // CSR build (once; reused by all 3 layers)
    hipMemsetAsync(deg, 0, (size_t)Nn * 4, stream);
    hist_dst<<<(E + 255) / 256, 256, 0, stream>>>(ei, deg, E);
    exscan<<<1, 1024, 0, stream>>>(deg, off, cursor, Nn);
    fill_csr<<<(E + 255) / 256, 256, 0, stream>>>(ei, cursor, csr, E);

    const dim3 gemmGrid((Nn + 127) / 128, 2);
    const int gatherBlocks = (Nn * 64 + 255) / 256;  // one wave per node

    // ---- layer 1 (F0=128: lane owns float2)
    gather_csr<2><<<gatherBlocks, 256, 0, stream>>>(x, agg, off, deg, csr, Nn);
    gemm_bias_relu<<<gemmGrid, 256, 0, stream>>>(agg, Wt1, b1, out, Nn, F0);

    // ---- layer 2 (F=256: lane owns float4)
    gather_csr<4><<<gatherBlocks, 256, 0, stream>>>(out, agg, off, deg, csr, Nn);
    gemm_bias_relu<<<gemmGrid, 256, 0, stream>>>(agg, Wt2, b2, out, Nn, F);

    // ---- layer 3
    gather_csr<4><<<gatherBlocks, 256, 0, stream>>>(out, agg, off, deg, csr, Nn);
    gemm_bias_relu<<<gemmGrid, 256, 0, stream>>>(agg, Wt3, b3, out, Nn, F);
}

// Round 3
// 445.182 us; speedup vs baseline: 15.2407x; 1.3407x over previous
//
#include <hip/hip_runtime.h>
#include <hip/hip_bf16.h>

// 3-layer GCN: per layer  out = relu(segment_sum(h[src] -> dst) @ W + b)
// Aggregate-first + CSR gather (no atomics, CSR built once, reused 3x).
// All inter-layer tensors carried in bf16 (MFMA consumes bf16 anyway);
// f32 accumulation in both gather and MFMA. Final output stored f32.

typedef short bf16x8 __attribute__((ext_vector_type(8)));
typedef float f32x4 __attribute__((ext_vector_type(4)));

__device__ __forceinline__ short f2bf(float f) {
    __hip_bfloat16 b = __float2bfloat16(f);
    return *reinterpret_cast<short*>(&b);
}
__device__ __forceinline__ float bf2f(short s) {
    union { unsigned u; float f; } c;
    c.u = ((unsigned)(unsigned short)s) << 16;
    return c.f;
}

// W [K][256] f32  ->  Wt [256][K] bf16 (transposed)
__global__ void wconvert(const float* __restrict__ W, short* __restrict__ Wt, int K) {
    int idx = blockIdx.x * blockDim.x + threadIdx.x;
    if (idx >= K * 256) return;
    int n = idx / K, k = idx - n * K;
    Wt[idx] = f2bf(W[k * 256 + n]);
}

// x f32 -> bf16 (vectorized 4/thread)
__global__ void xconvert(const float4* __restrict__ x, short* __restrict__ xb, int n4) {
    int idx = blockIdx.x * blockDim.x + threadIdx.x;
    if (idx >= n4) return;
    float4 v = x[idx];
    short tmp[4] = { f2bf(v.x), f2bf(v.y), f2bf(v.z), f2bf(v.w) };
    *reinterpret_cast<uint2*>(&xb[idx * 4]) = *reinterpret_cast<uint2*>(tmp);
}

// ---------------- CSR build (once per launch, reused 3x) ----------------

__global__ void hist_dst(const int* __restrict__ ei, int* __restrict__ deg, int E) {
    int e = blockIdx.x * blockDim.x + threadIdx.x;
    if (e < E) atomicAdd(&deg[ei[E + e]], 1);
}

__global__ void exscan(const int* __restrict__ deg, int* __restrict__ off,
                       int* __restrict__ cursor, int n) {
    __shared__ int part[1024];
    const int tid = threadIdx.x;
    const int chunk = (n + 1023) >> 10;
    const int s = tid * chunk;
    const int e = min(s + chunk, n);
    int sum = 0;
    for (int i = s; i < e; ++i) sum += deg[i];
    part[tid] = sum;
    __syncthreads();
    for (int d = 1; d < 1024; d <<= 1) {
        int v = (tid >= d) ? part[tid - d] : 0;
        __syncthreads();
        part[tid] += v;
        __syncthreads();
    }
    int base = (tid == 0) ? 0 : part[tid - 1];
    for (int i = s; i < e; ++i) {
        off[i] = base;
        cursor[i] = base;
        base += deg[i];
    }
}

__global__ void fill_csr(const int* __restrict__ ei, int* __restrict__ cursor,
                         int* __restrict__ csr, int E) {
    int e = blockIdx.x * blockDim.x + threadIdx.x;
    if (e < E) {
        int pos = atomicAdd(&cursor[ei[E + e]], 1);
        csr[pos] = ei[e];  // src
    }
}

// ------- CSR gather (bf16 in/out, f32 accum): one wave per node ----------
// VEC = bf16 elems per lane (2 for F=128, 4 for F=256)

template <int VEC>
__global__ void gather_csr_bf16(const short* __restrict__ h, short* __restrict__ agg,
                                const int* __restrict__ off, const int* __restrict__ deg,
                                const int* __restrict__ csr, int N) {
    typedef short svec __attribute__((ext_vector_type(VEC)));
    const int gw = (blockIdx.x * blockDim.x + threadIdx.x) >> 6;  // node id
    if (gw >= N) return;
    const int lane = threadIdx.x & 63;
    const int col = lane * VEC;
    const int F = 64 * VEC;
    const int base = off[gw];
    const int d = deg[gw];

    float acc[VEC];
#pragma unroll
    for (int q = 0; q < VEC; ++q) acc[q] = 0.0f;

    int j = 0;
    for (; j + 4 <= d; j += 4) {
        int s0 = csr[base + j], s1 = csr[base + j + 1];
        int s2 = csr[base + j + 2], s3 = csr[base + j + 3];
        svec v0 = *reinterpret_cast<const svec*>(h + (size_t)s0 * F + col);
        svec v1 = *reinterpret_cast<const svec*>(h + (size_t)s1 * F + col);
        svec v2 = *reinterpret_cast<const svec*>(h + (size_t)s2 * F + col);
        svec v3 = *reinterpret_cast<const svec*>(h + (size_t)s3 * F + col);
#pragma unroll
        for (int q = 0; q < VEC; ++q)
            acc[q] += (bf2f(v0[q]) + bf2f(v1[q])) + (bf2f(v2[q]) + bf2f(v3[q]));
    }
    for (; j < d; ++j) {
        int s = csr[base + j];
        svec v = *reinterpret_cast<const svec*>(h + (size_t)s * F + col);
#pragma unroll
        for (int q = 0; q < VEC; ++q) acc[q] += bf2f(v[q]);
    }
    svec o;
#pragma unroll
    for (int q = 0; q < VEC; ++q) o[q] = f2bf(acc[q]);
    *reinterpret_cast<svec*>(agg + (size_t)gw * F + col) = o;
}

// ------- GEMM: C[M,256] = relu(A[M,K] @ W[K,256] + bias) -----------------
// A bf16 [M][K], W transposed bf16 Wt[256][K]. 128x128 tile, 4 waves, 16x16x32.
// OutT: short -> store bf16 (inter-layer h); float -> store f32 (final out).

template <typename OutT>
__launch_bounds__(256)
__global__ void gemm_bias_relu(const short* __restrict__ A, const short* __restrict__ Wt,
                               const float* __restrict__ bias, OutT* __restrict__ out,
                               int M, int K) {
    __shared__ short As[128][72];  // +8 pad
    __shared__ short Bs[128][72];

    const int tid = threadIdx.x;
    const int lane = tid & 63, wid = tid >> 6;
    const int wr = wid >> 1, wc = wid & 1;
    const int lr = lane & 15, lg = lane >> 4;
    const int m0 = blockIdx.x * 128;
    const int n0 = blockIdx.y * 128;

    f32x4 acc[4][4];
#pragma unroll
    for (int i = 0; i < 4; ++i)
#pragma unroll
        for (int j = 0; j < 4; ++j)
#pragma unroll
            for (int r = 0; r < 4; ++r) acc[i][j][r] = 0.0f;

    const int srow = tid >> 2;          // 0..63
    const int scol = (tid & 3) << 4;    // 0,16,32,48 (shorts)

    for (int k0 = 0; k0 < K; k0 += 64) {
        __syncthreads();
#pragma unroll
        for (int pass = 0; pass < 2; ++pass) {
            int row = pass * 64 + srow;
            int gm = m0 + row;
            if (gm < M) {
                const uint4* ap = reinterpret_cast<const uint4*>(A + (size_t)gm * K + k0 + scol);
                *reinterpret_cast<uint4*>(&As[row][scol])     = ap[0];
                *reinterpret_cast<uint4*>(&As[row][scol + 8]) = ap[1];
            } else {
                uint4 z = {0, 0, 0, 0};
                *reinterpret_cast<uint4*>(&As[row][scol])     = z;
                *reinterpret_cast<uint4*>(&As[row][scol + 8]) = z;
            }
            const uint4* bp = reinterpret_cast<const uint4*>(Wt + (size_t)(n0 + row) * K + k0 + scol);
            *reinterpret_cast<uint4*>(&Bs[row][scol])     = bp[0];
            *reinterpret_cast<uint4*>(&Bs[row][scol + 8]) = bp[1];
        }
        __syncthreads();

#pragma unroll
        for (int ksub = 0; ksub < 2; ++ksub) {
            const int kb = ksub * 32 + 4 * lg;
            bf16x8 a[4], b[4];
#pragma unroll
            for (int mi = 0; mi < 4; ++mi) {
                int row = wr * 64 + mi * 16 + lr;
                uint2* pa = reinterpret_cast<uint2*>(&a[mi]);
                pa[0] = *reinterpret_cast<const uint2*>(&As[row][kb]);
                pa[1] = *reinterpret_cast<const uint2*>(&As[row][kb + 16]);
            }
#pragma unroll
            for (int ni = 0; ni < 4; ++ni) {
                int row = wc * 64 + ni * 16 + lr;
                uint2* pb = reinterpret_cast<uint2*>(&b[ni]);
                pb[0] = *reinterpret_cast<const uint2*>(&Bs[row][kb]);
                pb[1] = *reinterpret_cast<const uint2*>(&Bs[row][kb + 16]);
            }
#pragma unroll
            for (int mi = 0; mi < 4; ++mi)
#pragma unroll
                for (int ni = 0; ni < 4; ++ni)
                    acc[mi][ni] = __builtin_amdgcn_mfma_f32_16x16x32_bf16(a[mi], b[ni], acc[mi][ni], 0, 0, 0);
        }
    }

    float bv[4];
#pragma unroll
    for (int ni = 0; ni < 4; ++ni) bv[ni] = bias[n0 + wc * 64 + ni * 16 + lr];
#pragma unroll
    for (int mi = 0; mi < 4; ++mi) {
        int gmBase = m0 + wr * 64 + mi * 16 + 4 * lg;
#pragma unroll
        for (int r = 0; r < 4; ++r) {
            int gm = gmBase + r;
            if (gm >= M) continue;
#pragma unroll
            for (int ni = 0; ni < 4; ++ni) {
                int gn = n0 + wc * 64 + ni * 16 + lr;
                float v = acc[mi][ni][r] + bv[ni];
                v = v > 0.0f ? v : 0.0f;
                if constexpr (sizeof(OutT) == 2)
                    out[(size_t)gm * 256 + gn] = (OutT)f2bf(v);
                else
                    out[(size_t)gm * 256 + gn] = (OutT)v;
            }
        }
    }
}

extern "C" void kernel_launch(void* const* d_in, const int* in_sizes, int n_in,
                              void* d_out, int out_size, void* d_ws, size_t ws_size,
                              hipStream_t stream) {
    const float* x  = (const float*)d_in[0];
    const int*   ei = (const int*)d_in[1];
    const float* W1 = (const float*)d_in[2];
    const float* b1 = (const float*)d_in[3];
    const float* W2 = (const float*)d_in[4];
    const float* b2 = (const float*)d_in[5];
    const float* W3 = (const float*)d_in[6];
    const float* b3 = (const float*)d_in[7];
    float* out = (float*)d_out;
    short* hb  = (short*)d_out;  // inter-layer h (bf16) lives in d_out's space

    const int Nn = 50000, E = 800000, F0 = 128, F = 256;

    short* aggb = (short*)d_ws;                 // 50000*256 bf16 = 25.6 MB
    short* xb   = aggb + (size_t)Nn * F;        // 50000*128 bf16 = 12.8 MB
    short* Wt1  = xb + (size_t)Nn * F0;         // 128*256
    short* Wt2  = Wt1 + F0 * F;                 // 256*256
    short* Wt3  = Wt2 + F * F;
    int* deg    = (int*)(Wt3 + F * F);          // 200 KB
    int* off    = deg + Nn;
    int* cursor = off + Nn;
    int* csr    = cursor + Nn;                  // 3.2 MB

    // weights + x -> bf16
    wconvert<<<(F0 * F + 255) / 256, 256, 0, stream>>>(W1, Wt1, F0);
    wconvert<<<(F * F + 255) / 256, 256, 0, stream>>>(W2, Wt2, F);
    wconvert<<<(F * F + 255) / 256, 256, 0, stream>>>(W3, Wt3, F);
    xconvert<<<(Nn * F0 / 4 + 255) / 256, 256, 0, stream>>>((const float4*)x, xb, Nn * F0 / 4);

    // CSR build (once)
    hipMemsetAsync(deg, 0, (size_t)Nn * 4, stream);
    hist_dst<<<(E + 255) / 256, 256, 0, stream>>>(ei, deg, E);
    exscan<<<1, 1024, 0, stream>>>(deg, off, cursor, Nn);
    fill_csr<<<(E + 255) / 256, 256, 0, stream>>>(ei, cursor, csr, E);

    const dim3 gemmGrid((Nn + 127) / 128, 2);
    const int gatherBlocks = (Nn * 64 + 255) / 256;  // one wave per node

    // ---- layer 1 (F0=128: lane owns 2 bf16)
    gather_csr_bf16<2><<<gatherBlocks, 256, 0, stream>>>(xb, aggb, off, deg, csr, Nn);
    gemm_bias_relu<short><<<gemmGrid, 256, 0, stream>>>(aggb, Wt1, b1, hb, Nn, F0);

    // ---- layer 2 (F=256: lane owns 4 bf16)
    gather_csr_bf16<4><<<gatherBlocks, 256, 0, stream>>>(hb, aggb, off, deg, csr, Nn);
    gemm_bias_relu<short><<<gemmGrid, 256, 0, stream>>>(aggb, Wt2, b2, hb, Nn, F);

    // ---- layer 3 (final: f32 output)
    gather_csr_bf16<4><<<gatherBlocks, 256, 0, stream>>>(hb, aggb, off, deg, csr, Nn);
    gemm_bias_relu<float><<<gemmGrid, 256, 0, stream>>>(aggb, Wt3, b3, out, Nn, F);
}

// Round 4
// 348.227 us; speedup vs baseline: 19.4841x; 1.2784x over previous
//
#include <hip/hip_runtime.h>
#include <hip/hip_bf16.h>

// 3-layer GCN: per layer  out = relu(segment_sum(h[src] -> dst) @ W + b)
// Aggregate-first + CSR gather (no atomics, CSR built once, reused 3x).
// Inter-layer tensors in bf16 (MFMA consumes bf16 anyway); f32 accumulation
// in gather and MFMA. Final output f32. Hierarchical 3-kernel CSR scan.

typedef short bf16x8 __attribute__((ext_vector_type(8)));
typedef float f32x4 __attribute__((ext_vector_type(4)));

__device__ __forceinline__ short f2bf(float f) {
    __hip_bfloat16 b = __float2bfloat16(f);
    return *reinterpret_cast<short*>(&b);
}
__device__ __forceinline__ float bf2f(short s) {
    union { unsigned u; float f; } c;
    c.u = ((unsigned)(unsigned short)s) << 16;
    return c.f;
}

// W [K][256] f32  ->  Wt [256][K] bf16 (transposed)
__global__ void wconvert(const float* __restrict__ W, short* __restrict__ Wt, int K) {
    int idx = blockIdx.x * blockDim.x + threadIdx.x;
    if (idx >= K * 256) return;
    int n = idx / K, k = idx - n * K;
    Wt[idx] = f2bf(W[k * 256 + n]);
}

// x f32 -> bf16 (vectorized 4/thread)
__global__ void xconvert(const float4* __restrict__ x, short* __restrict__ xb, int n4) {
    int idx = blockIdx.x * blockDim.x + threadIdx.x;
    if (idx >= n4) return;
    float4 v = x[idx];
    short tmp[4] = { f2bf(v.x), f2bf(v.y), f2bf(v.z), f2bf(v.w) };
    *reinterpret_cast<uint2*>(&xb[idx * 4]) = *reinterpret_cast<uint2*>(tmp);
}

// ---------------- CSR build (once per launch, reused 3x) ----------------

__global__ void hist_dst(const int* __restrict__ ei, int* __restrict__ deg, int E) {
    int e = blockIdx.x * blockDim.x + threadIdx.x;
    if (e < E) atomicAdd(&deg[ei[E + e]], 1);
}

// 1) per-block sum of 256 degrees (coalesced + wave shuffle reduce)
__global__ void deg_block_sum(const int* __restrict__ deg, int* __restrict__ bsum, int n) {
    int i = blockIdx.x * 256 + threadIdx.x;
    int v = (i < n) ? deg[i] : 0;
#pragma unroll
    for (int o = 32; o > 0; o >>= 1) v += __shfl_down(v, o, 64);
    __shared__ int wsum[4];
    if ((threadIdx.x & 63) == 0) wsum[threadIdx.x >> 6] = v;
    __syncthreads();
    if (threadIdx.x == 0) bsum[blockIdx.x] = wsum[0] + wsum[1] + wsum[2] + wsum[3];
}

// 2) single-block exclusive scan of nb (<=256) block sums
__global__ void scan_bsum(const int* __restrict__ bsum, int* __restrict__ bbase, int nb) {
    __shared__ int lds[256];
    int v = (threadIdx.x < nb) ? bsum[threadIdx.x] : 0;
    lds[threadIdx.x] = v;
    __syncthreads();
    for (int d = 1; d < 256; d <<= 1) {
        int t = (threadIdx.x >= d) ? lds[threadIdx.x - d] : 0;
        __syncthreads();
        lds[threadIdx.x] += t;
        __syncthreads();
    }
    if (threadIdx.x < nb) bbase[threadIdx.x] = lds[threadIdx.x] - v;
}

// 3) per-block exclusive scan + base -> off, cursor
__global__ void scan_blocks(const int* __restrict__ deg, const int* __restrict__ bbase,
                            int* __restrict__ off, int* __restrict__ cursor, int n) {
    __shared__ int lds[256];
    int i = blockIdx.x * 256 + threadIdx.x;
    int v = (i < n) ? deg[i] : 0;
    lds[threadIdx.x] = v;
    __syncthreads();
    for (int d = 1; d < 256; d <<= 1) {
        int t = (threadIdx.x >= d) ? lds[threadIdx.x - d] : 0;
        __syncthreads();
        lds[threadIdx.x] += t;
        __syncthreads();
    }
    if (i < n) {
        int excl = lds[threadIdx.x] - v + bbase[blockIdx.x];
        off[i] = excl;
        cursor[i] = excl;
    }
}

__global__ void fill_csr(const int* __restrict__ ei, int* __restrict__ cursor,
                         int* __restrict__ csr, int E) {
    int e = blockIdx.x * blockDim.x + threadIdx.x;
    if (e < E) {
        int pos = atomicAdd(&cursor[ei[E + e]], 1);
        csr[pos] = ei[e];  // src
    }
}

// ------- CSR gather (bf16 in/out, f32 accum): one wave per node ----------

template <int VEC>
__global__ void gather_csr_bf16(const short* __restrict__ h, short* __restrict__ agg,
                                const int* __restrict__ off, const int* __restrict__ deg,
                                const int* __restrict__ csr, int N) {
    typedef short svec __attribute__((ext_vector_type(VEC)));
    const int gw = (blockIdx.x * blockDim.x + threadIdx.x) >> 6;  // node id
    if (gw >= N) return;
    const int lane = threadIdx.x & 63;
    const int col = lane * VEC;
    const int F = 64 * VEC;
    const int base = off[gw];
    const int d = deg[gw];

    float acc[VEC];
#pragma unroll
    for (int q = 0; q < VEC; ++q) acc[q] = 0.0f;

    int j = 0;
    for (; j + 4 <= d; j += 4) {
        int s0 = csr[base + j], s1 = csr[base + j + 1];
        int s2 = csr[base + j + 2], s3 = csr[base + j + 3];
        svec v0 = *reinterpret_cast<const svec*>(h + (size_t)s0 * F + col);
        svec v1 = *reinterpret_cast<const svec*>(h + (size_t)s1 * F + col);
        svec v2 = *reinterpret_cast<const svec*>(h + (size_t)s2 * F + col);
        svec v3 = *reinterpret_cast<const svec*>(h + (size_t)s3 * F + col);
#pragma unroll
        for (int q = 0; q < VEC; ++q)
            acc[q] += (bf2f(v0[q]) + bf2f(v1[q])) + (bf2f(v2[q]) + bf2f(v3[q]));
    }
    for (; j < d; ++j) {
        int s = csr[base + j];
        svec v = *reinterpret_cast<const svec*>(h + (size_t)s * F + col);
#pragma unroll
        for (int q = 0; q < VEC; ++q) acc[q] += bf2f(v[q]);
    }
    svec o;
#pragma unroll
    for (int q = 0; q < VEC; ++q) o[q] = f2bf(acc[q]);
    *reinterpret_cast<svec*>(agg + (size_t)gw * F + col) = o;
}

// ------- GEMM: C[M,256] = relu(A[M,K] @ W[K,256] + bias) -----------------
// A bf16 [M][K], W transposed bf16 Wt[256][K]. 128x128 tile, 4 waves, 16x16x32.

template <typename OutT>
__launch_bounds__(256)
__global__ void gemm_bias_relu(const short* __restrict__ A, const short* __restrict__ Wt,
                               const float* __restrict__ bias, OutT* __restrict__ out,
                               int M, int K) {
    __shared__ short As[128][72];  // +8 pad
    __shared__ short Bs[128][72];

    const int tid = threadIdx.x;
    const int lane = tid & 63, wid = tid >> 6;
    const int wr = wid >> 1, wc = wid & 1;
    const int lr = lane & 15, lg = lane >> 4;
    const int m0 = blockIdx.x * 128;
    const int n0 = blockIdx.y * 128;

    f32x4 acc[4][4];
#pragma unroll
    for (int i = 0; i < 4; ++i)
#pragma unroll
        for (int j = 0; j < 4; ++j)
#pragma unroll
            for (int r = 0; r < 4; ++r) acc[i][j][r] = 0.0f;

    const int srow = tid >> 2;          // 0..63
    const int scol = (tid & 3) << 4;    // 0,16,32,48 (shorts)

    for (int k0 = 0; k0 < K; k0 += 64) {
        __syncthreads();
#pragma unroll
        for (int pass = 0; pass < 2; ++pass) {
            int row = pass * 64 + srow;
            int gm = m0 + row;
            if (gm < M) {
                const uint4* ap = reinterpret_cast<const uint4*>(A + (size_t)gm * K + k0 + scol);
                *reinterpret_cast<uint4*>(&As[row][scol])     = ap[0];
                *reinterpret_cast<uint4*>(&As[row][scol + 8]) = ap[1];
            } else {
                uint4 z = {0, 0, 0, 0};
                *reinterpret_cast<uint4*>(&As[row][scol])     = z;
                *reinterpret_cast<uint4*>(&As[row][scol + 8]) = z;
            }
            const uint4* bp = reinterpret_cast<const uint4*>(Wt + (size_t)(n0 + row) * K + k0 + scol);
            *reinterpret_cast<uint4*>(&Bs[row][scol])     = bp[0];
            *reinterpret_cast<uint4*>(&Bs[row][scol + 8]) = bp[1];
        }
        __syncthreads();

#pragma unroll
        for (int ksub = 0; ksub < 2; ++ksub) {
            const int kb = ksub * 32 + 4 * lg;
            bf16x8 a[4], b[4];
#pragma unroll
            for (int mi = 0; mi < 4; ++mi) {
                int row = wr * 64 + mi * 16 + lr;
                uint2* pa = reinterpret_cast<uint2*>(&a[mi]);
                pa[0] = *reinterpret_cast<const uint2*>(&As[row][kb]);
                pa[1] = *reinterpret_cast<const uint2*>(&As[row][kb + 16]);
            }
#pragma unroll
            for (int ni = 0; ni < 4; ++ni) {
                int row = wc * 64 + ni * 16 + lr;
                uint2* pb = reinterpret_cast<uint2*>(&b[ni]);
                pb[0] = *reinterpret_cast<const uint2*>(&Bs[row][kb]);
                pb[1] = *reinterpret_cast<const uint2*>(&Bs[row][kb + 16]);
            }
#pragma unroll
            for (int mi = 0; mi < 4; ++mi)
#pragma unroll
                for (int ni = 0; ni < 4; ++ni)
                    acc[mi][ni] = __builtin_amdgcn_mfma_f32_16x16x32_bf16(a[mi], b[ni], acc[mi][ni], 0, 0, 0);
        }
    }

    float bv[4];
#pragma unroll
    for (int ni = 0; ni < 4; ++ni) bv[ni] = bias[n0 + wc * 64 + ni * 16 + lr];
#pragma unroll
    for (int mi = 0; mi < 4; ++mi) {
        int gmBase = m0 + wr * 64 + mi * 16 + 4 * lg;
#pragma unroll
        for (int r = 0; r < 4; ++r) {
            int gm = gmBase + r;
            if (gm >= M) continue;
#pragma unroll
            for (int ni = 0; ni < 4; ++ni) {
                int gn = n0 + wc * 64 + ni * 16 + lr;
                float v = acc[mi][ni][r] + bv[ni];
                v = v > 0.0f ? v : 0.0f;
                if constexpr (sizeof(OutT) == 2)
                    out[(size_t)gm * 256 + gn] = (OutT)f2bf(v);
                else
                    out[(size_t)gm * 256 + gn] = (OutT)v;
            }
        }
    }
}

extern "C" void kernel_launch(void* const* d_in, const int* in_sizes, int n_in,
                              void* d_out, int out_size, void* d_ws, size_t ws_size,
                              hipStream_t stream) {
    const float* x  = (const float*)d_in[0];
    const int*   ei = (const int*)d_in[1];
    const float* W1 = (const float*)d_in[2];
    const float* b1 = (const float*)d_in[3];
    const float* W2 = (const float*)d_in[4];
    const float* b2 = (const float*)d_in[5];
    const float* W3 = (const float*)d_in[6];
    const float* b3 = (const float*)d_in[7];
    float* out = (float*)d_out;
    short* hb  = (short*)d_out;  // inter-layer h (bf16) lives in d_out's space

    const int Nn = 50000, E = 800000, F0 = 128, F = 256;
    const int NB = (Nn + 255) / 256;  // 196 scan blocks

    short* aggb = (short*)d_ws;                 // 25.6 MB
    short* xb   = aggb + (size_t)Nn * F;        // 12.8 MB
    short* Wt1  = xb + (size_t)Nn * F0;
    short* Wt2  = Wt1 + F0 * F;
    short* Wt3  = Wt2 + F * F;
    int* deg    = (int*)(Wt3 + F * F);
    int* off    = deg + Nn;
    int* cursor = off + Nn;
    int* bsum   = cursor + Nn;                  // NB ints
    int* bbase  = bsum + NB;                    // NB ints
    int* csr    = bbase + NB;                   // 3.2 MB

    // weights + x -> bf16
    wconvert<<<(F0 * F + 255) / 256, 256, 0, stream>>>(W1, Wt1, F0);
    wconvert<<<(F * F + 255) / 256, 256, 0, stream>>>(W2, Wt2, F);
    wconvert<<<(F * F + 255) / 256, 256, 0, stream>>>(W3, Wt3, F);
    xconvert<<<(Nn * F0 / 4 + 255) / 256, 256, 0, stream>>>((const float4*)x, xb, Nn * F0 / 4);

    // CSR build (once): hist -> hierarchical scan -> fill
    hipMemsetAsync(deg, 0, (size_t)Nn * 4, stream);
    hist_dst<<<(E + 255) / 256, 256, 0, stream>>>(ei, deg, E);
    deg_block_sum<<<NB, 256, 0, stream>>>(deg, bsum, Nn);
    scan_bsum<<<1, 256, 0, stream>>>(bsum, bbase, NB);
    scan_blocks<<<NB, 256, 0, stream>>>(deg, bbase, off, cursor, Nn);
    fill_csr<<<(E + 255) / 256, 256, 0, stream>>>(ei, cursor, csr, E);

    const dim3 gemmGrid((Nn + 127) / 128, 2);
    const int gatherBlocks = (Nn * 64 + 255) / 256;  // one wave per node

    // ---- layer 1 (F0=128: lane owns 2 bf16)
    gather_csr_bf16<2><<<gatherBlocks, 256, 0, stream>>>(xb, aggb, off, deg, csr, Nn);
    gemm_bias_relu<short><<<gemmGrid, 256, 0, stream>>>(aggb, Wt1, b1, hb, Nn, F0);

    // ---- layer 2 (F=256: lane owns 4 bf16)
    gather_csr_bf16<4><<<gatherBlocks, 256, 0, stream>>>(hb, aggb, off, deg, csr, Nn);
    gemm_bias_relu<short><<<gemmGrid, 256, 0, stream>>>(aggb, Wt2, b2, hb, Nn, F);

    // ---- layer 3 (final: f32 output)
    gather_csr_bf16<4><<<gatherBlocks, 256, 0, stream>>>(hb, aggb, off, deg, csr, Nn);
    gemm_bias_relu<float><<<gemmGrid, 256, 0, stream>>>(aggb, Wt3, b3, out, Nn, F);
}

// Round 5
// 302.058 us; speedup vs baseline: 22.4623x; 1.1529x over previous
//
#include <hip/hip_runtime.h>
#include <hip/hip_bf16.h>

// 3-layer GCN: per layer  out = relu(segment_sum(h[src] -> dst) @ W + b)
// Aggregate-first + CSR gather (no atomics in hot path; CSR built once,
// reused 3x). CSR build is a two-level binned counting sort so all
// scattered writes stay L2-local (no 64B-line write amplification).
// Inter-layer tensors bf16; f32 accumulation in gather and MFMA.

#define NBIN 98      // ceil(50000/512) coarse bins
#define BINSH 9      // 512 nodes per bin

typedef short bf16x8 __attribute__((ext_vector_type(8)));
typedef float f32x4 __attribute__((ext_vector_type(4)));

__device__ __forceinline__ short f2bf(float f) {
    __hip_bfloat16 b = __float2bfloat16(f);
    return *reinterpret_cast<short*>(&b);
}
__device__ __forceinline__ float bf2f(short s) {
    union { unsigned u; float f; } c;
    c.u = ((unsigned)(unsigned short)s) << 16;
    return c.f;
}

// W [K][256] f32  ->  Wt [256][K] bf16 (transposed)
__global__ void wconvert(const float* __restrict__ W, short* __restrict__ Wt, int K) {
    int idx = blockIdx.x * blockDim.x + threadIdx.x;
    if (idx >= K * 256) return;
    int n = idx / K, k = idx - n * K;
    Wt[idx] = f2bf(W[k * 256 + n]);
}

// x f32 -> bf16
__global__ void xconvert(const float4* __restrict__ x, short* __restrict__ xb, int n4) {
    int idx = blockIdx.x * blockDim.x + threadIdx.x;
    if (idx >= n4) return;
    float4 v = x[idx];
    short tmp[4] = { f2bf(v.x), f2bf(v.y), f2bf(v.z), f2bf(v.w) };
    *reinterpret_cast<uint2*>(&xb[idx * 4]) = *reinterpret_cast<uint2*>(tmp);
}

// ---------------- CSR build: two-level binned counting sort --------------

// 1) coarse histogram over NBIN bins (LDS-staged, ~19k global atomics total)
__global__ void coarse_hist(const int* __restrict__ ei, int* __restrict__ cbin, int E) {
    __shared__ int h[NBIN];
    for (int i = threadIdx.x; i < NBIN; i += 256) h[i] = 0;
    __syncthreads();
    int base = blockIdx.x * 4096;
#pragma unroll
    for (int i = 0; i < 16; ++i) {
        int e = base + i * 256 + threadIdx.x;
        if (e < E) atomicAdd(&h[ei[E + e] >> BINSH], 1);
    }
    __syncthreads();
    for (int i = threadIdx.x; i < NBIN; i += 256)
        if (h[i]) atomicAdd(&cbin[i], h[i]);
}

// 2) exclusive scan of NBIN coarse counts -> cstart[0..NBIN], gcursor
__global__ void coarse_scan(const int* __restrict__ cbin, int* __restrict__ cstart,
                            int* __restrict__ gcursor, int E) {
    __shared__ int lds[128];
    int v = (threadIdx.x < NBIN) ? cbin[threadIdx.x] : 0;
    lds[threadIdx.x] = v;
    __syncthreads();
    for (int d = 1; d < 128; d <<= 1) {
        int t = (threadIdx.x >= d) ? lds[threadIdx.x - d] : 0;
        __syncthreads();
        lds[threadIdx.x] += t;
        __syncthreads();
    }
    if (threadIdx.x < NBIN) {
        int ex = lds[threadIdx.x] - v;
        cstart[threadIdx.x] = ex;
        gcursor[threadIdx.x] = ex;
    }
    if (threadIdx.x == 0) cstart[NBIN] = E;
}

// 3) append edges into per-bin regions as packed (localdst<<16 | src)
__global__ void bin_fill(const int* __restrict__ ei, int* __restrict__ gcursor,
                         unsigned* __restrict__ staging, int E) {
    __shared__ int h[NBIN];
    __shared__ int cur[NBIN];
    for (int i = threadIdx.x; i < NBIN; i += 256) h[i] = 0;
    __syncthreads();
    int base = blockIdx.x * 4096;
    int d_[16], s_[16];
#pragma unroll
    for (int i = 0; i < 16; ++i) {
        int e = base + i * 256 + threadIdx.x;
        if (e < E) {
            s_[i] = ei[e];
            d_[i] = ei[E + e];
            atomicAdd(&h[d_[i] >> BINSH], 1);
        } else d_[i] = -1;
    }
    __syncthreads();
    for (int i = threadIdx.x; i < NBIN; i += 256)
        cur[i] = h[i] ? atomicAdd(&gcursor[i], h[i]) : 0;
    __syncthreads();
#pragma unroll
    for (int i = 0; i < 16; ++i) {
        if (d_[i] >= 0) {
            int p = atomicAdd(&cur[d_[i] >> BINSH], 1);
            staging[p] = ((unsigned)(d_[i] & 511) << 16) | (unsigned)s_[i];
        }
    }
}

// 4) per-bin degree histogram -> deg (coalesced write, no scattered atomics)
__global__ void bin_deg(const unsigned* __restrict__ staging, const int* __restrict__ cstart,
                        int* __restrict__ deg, int N) {
    __shared__ int cnt[512];
    int b = blockIdx.x;
    for (int i = threadIdx.x; i < 512; i += 256) cnt[i] = 0;
    __syncthreads();
    int s = cstart[b], e = cstart[b + 1];
    for (int p = s + threadIdx.x; p < e; p += 256)
        atomicAdd(&cnt[staging[p] >> 16], 1);
    __syncthreads();
    int nb0 = b << BINSH;
    for (int i = threadIdx.x; i < 512; i += 256)
        if (nb0 + i < N) deg[nb0 + i] = cnt[i];
}

// scan of deg -> off (hierarchical, 3 kernels)
__global__ void deg_block_sum(const int* __restrict__ deg, int* __restrict__ bsum, int n) {
    int i = blockIdx.x * 256 + threadIdx.x;
    int v = (i < n) ? deg[i] : 0;
#pragma unroll
    for (int o = 32; o > 0; o >>= 1) v += __shfl_down(v, o, 64);
    __shared__ int wsum[4];
    if ((threadIdx.x & 63) == 0) wsum[threadIdx.x >> 6] = v;
    __syncthreads();
    if (threadIdx.x == 0) bsum[blockIdx.x] = wsum[0] + wsum[1] + wsum[2] + wsum[3];
}

__global__ void scan_bsum(const int* __restrict__ bsum, int* __restrict__ bbase, int nb) {
    __shared__ int lds[256];
    int v = (threadIdx.x < nb) ? bsum[threadIdx.x] : 0;
    lds[threadIdx.x] = v;
    __syncthreads();
    for (int d = 1; d < 256; d <<= 1) {
        int t = (threadIdx.x >= d) ? lds[threadIdx.x - d] : 0;
        __syncthreads();
        lds[threadIdx.x] += t;
        __syncthreads();
    }
    if (threadIdx.x < nb) bbase[threadIdx.x] = lds[threadIdx.x] - v;
}

__global__ void scan_blocks(const int* __restrict__ deg, const int* __restrict__ bbase,
                            int* __restrict__ off, int n) {
    __shared__ int lds[256];
    int i = blockIdx.x * 256 + threadIdx.x;
    int v = (i < n) ? deg[i] : 0;
    lds[threadIdx.x] = v;
    __syncthreads();
    for (int d = 1; d < 256; d <<= 1) {
        int t = (threadIdx.x >= d) ? lds[threadIdx.x - d] : 0;
        __syncthreads();
        lds[threadIdx.x] += t;
        __syncthreads();
    }
    if (i < n) off[i] = lds[threadIdx.x] - v + bbase[blockIdx.x];
}

// 5) place: per-bin LDS cursors from off, scatter src within L2-local region
__global__ void bin_place(const unsigned* __restrict__ staging, const int* __restrict__ cstart,
                          const int* __restrict__ off, int* __restrict__ csr, int N) {
    __shared__ int cur[512];
    int b = blockIdx.x;
    int nb0 = b << BINSH;
    for (int i = threadIdx.x; i < 512; i += 256)
        cur[i] = (nb0 + i < N) ? off[nb0 + i] : 0;
    __syncthreads();
    int s = cstart[b], e = cstart[b + 1];
    for (int p = s + threadIdx.x; p < e; p += 256) {
        unsigned v = staging[p];
        int pos = atomicAdd(&cur[v >> 16], 1);
        csr[pos] = (int)(v & 0xFFFFu);
    }
}

// ------- CSR gather (bf16 in/out, f32 accum): one wave per node ----------

template <int VEC>
__global__ void gather_csr_bf16(const short* __restrict__ h, short* __restrict__ agg,
                                const int* __restrict__ off, const int* __restrict__ deg,
                                const int* __restrict__ csr, int N) {
    typedef short svec __attribute__((ext_vector_type(VEC)));
    const int gw = (blockIdx.x * blockDim.x + threadIdx.x) >> 6;  // node id
    if (gw >= N) return;
    const int lane = threadIdx.x & 63;
    const int col = lane * VEC;
    const int F = 64 * VEC;
    const int base = off[gw];
    const int d = deg[gw];

    float acc[VEC];
#pragma unroll
    for (int q = 0; q < VEC; ++q) acc[q] = 0.0f;

    int j = 0;
    for (; j + 4 <= d; j += 4) {
        int s0 = csr[base + j], s1 = csr[base + j + 1];
        int s2 = csr[base + j + 2], s3 = csr[base + j + 3];
        svec v0 = *reinterpret_cast<const svec*>(h + (size_t)s0 * F + col);
        svec v1 = *reinterpret_cast<const svec*>(h + (size_t)s1 * F + col);
        svec v2 = *reinterpret_cast<const svec*>(h + (size_t)s2 * F + col);
        svec v3 = *reinterpret_cast<const svec*>(h + (size_t)s3 * F + col);
#pragma unroll
        for (int q = 0; q < VEC; ++q)
            acc[q] += (bf2f(v0[q]) + bf2f(v1[q])) + (bf2f(v2[q]) + bf2f(v3[q]));
    }
    for (; j < d; ++j) {
        int s = csr[base + j];
        svec v = *reinterpret_cast<const svec*>(h + (size_t)s * F + col);
#pragma unroll
        for (int q = 0; q < VEC; ++q) acc[q] += bf2f(v[q]);
    }
    svec o;
#pragma unroll
    for (int q = 0; q < VEC; ++q) o[q] = f2bf(acc[q]);
    *reinterpret_cast<svec*>(agg + (size_t)gw * F + col) = o;
}

// ------- GEMM: C[M,256] = relu(A[M,K] @ W[K,256] + bias) -----------------

template <typename OutT>
__launch_bounds__(256)
__global__ void gemm_bias_relu(const short* __restrict__ A, const short* __restrict__ Wt,
                               const float* __restrict__ bias, OutT* __restrict__ out,
                               int M, int K) {
    __shared__ short As[128][72];  // +8 pad
    __shared__ short Bs[128][72];

    const int tid = threadIdx.x;
    const int lane = tid & 63, wid = tid >> 6;
    const int wr = wid >> 1, wc = wid & 1;
    const int lr = lane & 15, lg = lane >> 4;
    const int m0 = blockIdx.x * 128;
    const int n0 = blockIdx.y * 128;

    f32x4 acc[4][4];
#pragma unroll
    for (int i = 0; i < 4; ++i)
#pragma unroll
        for (int j = 0; j < 4; ++j)
#pragma unroll
            for (int r = 0; r < 4; ++r) acc[i][j][r] = 0.0f;

    const int srow = tid >> 2;          // 0..63
    const int scol = (tid & 3) << 4;    // 0,16,32,48 (shorts)

    for (int k0 = 0; k0 < K; k0 += 64) {
        __syncthreads();
#pragma unroll
        for (int pass = 0; pass < 2; ++pass) {
            int row = pass * 64 + srow;
            int gm = m0 + row;
            if (gm < M) {
                const uint4* ap = reinterpret_cast<const uint4*>(A + (size_t)gm * K + k0 + scol);
                *reinterpret_cast<uint4*>(&As[row][scol])     = ap[0];
                *reinterpret_cast<uint4*>(&As[row][scol + 8]) = ap[1];
            } else {
                uint4 z = {0, 0, 0, 0};
                *reinterpret_cast<uint4*>(&As[row][scol])     = z;
                *reinterpret_cast<uint4*>(&As[row][scol + 8]) = z;
            }
            const uint4* bp = reinterpret_cast<const uint4*>(Wt + (size_t)(n0 + row) * K + k0 + scol);
            *reinterpret_cast<uint4*>(&Bs[row][scol])     = bp[0];
            *reinterpret_cast<uint4*>(&Bs[row][scol + 8]) = bp[1];
        }
        __syncthreads();

#pragma unroll
        for (int ksub = 0; ksub < 2; ++ksub) {
            const int kb = ksub * 32 + 4 * lg;
            bf16x8 a[4], b[4];
#pragma unroll
            for (int mi = 0; mi < 4; ++mi) {
                int row = wr * 64 + mi * 16 + lr;
                uint2* pa = reinterpret_cast<uint2*>(&a[mi]);
                pa[0] = *reinterpret_cast<const uint2*>(&As[row][kb]);
                pa[1] = *reinterpret_cast<const uint2*>(&As[row][kb + 16]);
            }
#pragma unroll
            for (int ni = 0; ni < 4; ++ni) {
                int row = wc * 64 + ni * 16 + lr;
                uint2* pb = reinterpret_cast<uint2*>(&b[ni]);
                pb[0] = *reinterpret_cast<const uint2*>(&Bs[row][kb]);
                pb[1] = *reinterpret_cast<const uint2*>(&Bs[row][kb + 16]);
            }
#pragma unroll
            for (int mi = 0; mi < 4; ++mi)
#pragma unroll
                for (int ni = 0; ni < 4; ++ni)
                    acc[mi][ni] = __builtin_amdgcn_mfma_f32_16x16x32_bf16(a[mi], b[ni], acc[mi][ni], 0, 0, 0);
        }
    }

    float bv[4];
#pragma unroll
    for (int ni = 0; ni < 4; ++ni) bv[ni] = bias[n0 + wc * 64 + ni * 16 + lr];
#pragma unroll
    for (int mi = 0; mi < 4; ++mi) {
        int gmBase = m0 + wr * 64 + mi * 16 + 4 * lg;
#pragma unroll
        for (int r = 0; r < 4; ++r) {
            int gm = gmBase + r;
            if (gm >= M) continue;
#pragma unroll
            for (int ni = 0; ni < 4; ++ni) {
                int gn = n0 + wc * 64 + ni * 16 + lr;
                float v = acc[mi][ni][r] + bv[ni];
                v = v > 0.0f ? v : 0.0f;
                if constexpr (sizeof(OutT) == 2)
                    out[(size_t)gm * 256 + gn] = (OutT)f2bf(v);
                else
                    out[(size_t)gm * 256 + gn] = (OutT)v;
            }
        }
    }
}

extern "C" void kernel_launch(void* const* d_in, const int* in_sizes, int n_in,
                              void* d_out, int out_size, void* d_ws, size_t ws_size,
                              hipStream_t stream) {
    const float* x  = (const float*)d_in[0];
    const int*   ei = (const int*)d_in[1];
    const float* W1 = (const float*)d_in[2];
    const float* b1 = (const float*)d_in[3];
    const float* W2 = (const float*)d_in[4];
    const float* b2 = (const float*)d_in[5];
    const float* W3 = (const float*)d_in[6];
    const float* b3 = (const float*)d_in[7];
    float* out = (float*)d_out;
    short* hb  = (short*)d_out;  // inter-layer h (bf16) lives in d_out's space

    const int Nn = 50000, E = 800000, F0 = 128, F = 256;
    const int NB = (Nn + 255) / 256;       // deg-scan blocks
    const int EB = (E + 4095) / 4096;      // edge-binning blocks

    short* aggb = (short*)d_ws;                 // 25.6 MB
    short* xb   = aggb + (size_t)Nn * F;        // 12.8 MB
    short* Wt1  = xb + (size_t)Nn * F0;
    short* Wt2  = Wt1 + F0 * F;
    short* Wt3  = Wt2 + F * F;
    int* deg     = (int*)(Wt3 + F * F);         // 200 KB
    int* off     = deg + Nn;                    // 200 KB
    int* bsum    = off + Nn;                    // NB
    int* bbase   = bsum + NB;                   // NB
    int* cbin    = bbase + NB;                  // NBIN
    int* cstart  = cbin + NBIN;                 // NBIN+1
    int* gcursor = cstart + NBIN + 1;           // NBIN
    unsigned* staging = (unsigned*)(gcursor + NBIN);  // 3.2 MB
    int* csr     = (int*)(staging + E);         // 3.2 MB

    // weights + x -> bf16
    wconvert<<<(F0 * F + 255) / 256, 256, 0, stream>>>(W1, Wt1, F0);
    wconvert<<<(F * F + 255) / 256, 256, 0, stream>>>(W2, Wt2, F);
    wconvert<<<(F * F + 255) / 256, 256, 0, stream>>>(W3, Wt3, F);
    xconvert<<<(Nn * F0 / 4 + 255) / 256, 256, 0, stream>>>((const float4*)x, xb, Nn * F0 / 4);

    // CSR build: coarse-bin -> fill -> deg -> scan -> place
    hipMemsetAsync(cbin, 0, NBIN * 4, stream);
    coarse_hist<<<EB, 256, 0, stream>>>(ei, cbin, E);
    coarse_scan<<<1, 128, 0, stream>>>(cbin, cstart, gcursor, E);
    bin_fill<<<EB, 256, 0, stream>>>(ei, gcursor, staging, E);
    bin_deg<<<NBIN, 256, 0, stream>>>(staging, cstart, deg, Nn);
    deg_block_sum<<<NB, 256, 0, stream>>>(deg, bsum, Nn);
    scan_bsum<<<1, 256, 0, stream>>>(bsum, bbase, NB);
    scan_blocks<<<NB, 256, 0, stream>>>(deg, bbase, off, Nn);
    bin_place<<<NBIN, 256, 0, stream>>>(staging, cstart, off, csr, Nn);

    const dim3 gemmGrid((Nn + 127) / 128, 2);
    const int gatherBlocks = (Nn * 64 + 255) / 256;  // one wave per node

    // ---- layer 1 (F0=128: lane owns 2 bf16)
    gather_csr_bf16<2><<<gatherBlocks, 256, 0, stream>>>(xb, aggb, off, deg, csr, Nn);
    gemm_bias_relu<short><<<gemmGrid, 256, 0, stream>>>(aggb, Wt1, b1, hb, Nn, F0);

    // ---- layer 2 (F=256: lane owns 4 bf16)
    gather_csr_bf16<4><<<gatherBlocks, 256, 0, stream>>>(hb, aggb, off, deg, csr, Nn);
    gemm_bias_relu<short><<<gemmGrid, 256, 0, stream>>>(aggb, Wt2, b2, hb, Nn, F);

    // ---- layer 3 (final: f32 output)
    gather_csr_bf16<4><<<gatherBlocks, 256, 0, stream>>>(hb, aggb, off, deg, csr, Nn);
    gemm_bias_relu<float><<<gemmGrid, 256, 0, stream>>>(aggb, Wt3, b3, out, Nn, F);
}

// Round 6
// 264.886 us; speedup vs baseline: 25.6144x; 1.1403x over previous
//
#include <hip/hip_runtime.h>
#include <hip/hip_bf16.h>

// 3-layer GCN: per layer  out = relu(segment_sum(h[src] -> dst) @ W + b)
// Aggregate-first + CSR gather. CSR built once via two-level binned
// counting sort (all scattered writes L2-local); global off derived from
// bin-local scans (bins tile the edge array contiguously). Inter-layer
// tensors bf16; f32 accumulation in gather and MFMA.

#define NBIN 98      // ceil(50000/512) coarse bins
#define BINSH 9      // 512 nodes per bin

typedef short bf16x8 __attribute__((ext_vector_type(8)));
typedef float f32x4 __attribute__((ext_vector_type(4)));

__device__ __forceinline__ short f2bf(float f) {
    __hip_bfloat16 b = __float2bfloat16(f);
    return *reinterpret_cast<short*>(&b);
}
__device__ __forceinline__ float bf2f(short s) {
    union { unsigned u; float f; } c;
    c.u = ((unsigned)(unsigned short)s) << 16;
    return c.f;
}

// fused prep: W1,W2,W3 -> transposed bf16; x -> bf16
__global__ void prep(const float* __restrict__ W1, const float* __restrict__ W2,
                     const float* __restrict__ W3, const float4* __restrict__ x,
                     short* __restrict__ Wt1, short* __restrict__ Wt2,
                     short* __restrict__ Wt3, short* __restrict__ xb) {
    int idx = blockIdx.x * 256 + threadIdx.x;
    if (idx < 32768) {            // W1t [256][128]
        int n = idx >> 7, k = idx & 127;
        Wt1[idx] = f2bf(W1[k * 256 + n]);
    } else if (idx < 98304) {     // W2t [256][256]
        int i = idx - 32768, n = i >> 8, k = i & 255;
        Wt2[i] = f2bf(W2[k * 256 + n]);
    } else if (idx < 163840) {    // W3t [256][256]
        int i = idx - 98304, n = i >> 8, k = i & 255;
        Wt3[i] = f2bf(W3[k * 256 + n]);
    } else {                      // x: 1.6M float4 units
        int i = idx - 163840;
        if (i < 1600000) {
            float4 v = x[i];
            short tmp[4] = { f2bf(v.x), f2bf(v.y), f2bf(v.z), f2bf(v.w) };
            *reinterpret_cast<uint2*>(&xb[i * 4]) = *reinterpret_cast<uint2*>(tmp);
        }
    }
}

// ---------------- CSR build: two-level binned counting sort --------------

// 1) coarse histogram over NBIN bins
__global__ void coarse_hist(const int* __restrict__ ei, int* __restrict__ cbin, int E) {
    __shared__ int h[NBIN];
    for (int i = threadIdx.x; i < NBIN; i += 256) h[i] = 0;
    __syncthreads();
    int base = blockIdx.x * 4096;
#pragma unroll
    for (int i = 0; i < 16; ++i) {
        int e = base + i * 256 + threadIdx.x;
        if (e < E) atomicAdd(&h[ei[E + e] >> BINSH], 1);
    }
    __syncthreads();
    for (int i = threadIdx.x; i < NBIN; i += 256)
        if (h[i]) atomicAdd(&cbin[i], h[i]);
}

// 2) exclusive scan of NBIN coarse counts -> cstart[0..NBIN], gcursor; off[N]=E
__global__ void coarse_scan(const int* __restrict__ cbin, int* __restrict__ cstart,
                            int* __restrict__ gcursor, int* __restrict__ off,
                            int E, int N) {
    __shared__ int lds[128];
    int v = (threadIdx.x < NBIN) ? cbin[threadIdx.x] : 0;
    lds[threadIdx.x] = v;
    __syncthreads();
    for (int d = 1; d < 128; d <<= 1) {
        int t = (threadIdx.x >= d) ? lds[threadIdx.x - d] : 0;
        __syncthreads();
        lds[threadIdx.x] += t;
        __syncthreads();
    }
    if (threadIdx.x < NBIN) {
        int ex = lds[threadIdx.x] - v;
        cstart[threadIdx.x] = ex;
        gcursor[threadIdx.x] = ex;
    }
    if (threadIdx.x == 0) { cstart[NBIN] = E; off[N] = E; }
}

// 3) append edges into per-bin regions as packed (localdst<<16 | src)
__global__ void bin_fill(const int* __restrict__ ei, int* __restrict__ gcursor,
                         unsigned* __restrict__ staging, int E) {
    __shared__ int h[NBIN];
    __shared__ int cur[NBIN];
    for (int i = threadIdx.x; i < NBIN; i += 256) h[i] = 0;
    __syncthreads();
    int base = blockIdx.x * 4096;
    int d_[16], s_[16];
#pragma unroll
    for (int i = 0; i < 16; ++i) {
        int e = base + i * 256 + threadIdx.x;
        if (e < E) {
            s_[i] = ei[e];
            d_[i] = ei[E + e];
            atomicAdd(&h[d_[i] >> BINSH], 1);
        } else d_[i] = -1;
    }
    __syncthreads();
    for (int i = threadIdx.x; i < NBIN; i += 256)
        cur[i] = h[i] ? atomicAdd(&gcursor[i], h[i]) : 0;
    __syncthreads();
#pragma unroll
    for (int i = 0; i < 16; ++i) {
        if (d_[i] >= 0) {
            int p = atomicAdd(&cur[d_[i] >> BINSH], 1);
            staging[p] = ((unsigned)(d_[i] & 511) << 16) | (unsigned)s_[i];
        }
    }
}

// 4) per-bin: count -> local excl scan -> off (global) -> place csr.
//    Bins tile the edge array contiguously, so off is globally consistent.
__global__ void bin_finalize(const unsigned* __restrict__ staging,
                             const int* __restrict__ cstart,
                             int* __restrict__ off, int* __restrict__ csr, int N) {
    __shared__ int cnt[512];
    __shared__ int psum[256];
    __shared__ int cur[512];
    const int b = blockIdx.x, t = threadIdx.x;
    cnt[t] = 0; cnt[t + 256] = 0;
    __syncthreads();
    const int s = cstart[b], e = cstart[b + 1];
    for (int p = s + t; p < e; p += 256) atomicAdd(&cnt[staging[p] >> 16], 1);
    __syncthreads();
    int c0 = cnt[2 * t], c1 = cnt[2 * t + 1];
    psum[t] = c0 + c1;
    __syncthreads();
    for (int d = 1; d < 256; d <<= 1) {
        int v = (t >= d) ? psum[t - d] : 0;
        __syncthreads();
        psum[t] += v;
        __syncthreads();
    }
    int base = s + (t ? psum[t - 1] : 0);
    int nb0 = b << BINSH;
    cur[2 * t] = base;
    cur[2 * t + 1] = base + c0;
    if (nb0 + 2 * t < N)     off[nb0 + 2 * t]     = base;
    if (nb0 + 2 * t + 1 < N) off[nb0 + 2 * t + 1] = base + c0;
    __syncthreads();
    for (int p = s + t; p < e; p += 256) {
        unsigned v = staging[p];
        int pos = atomicAdd(&cur[v >> 16], 1);
        csr[pos] = (int)(v & 0xFFFFu);
    }
}

// ------- CSR gather (bf16 in/out, f32 accum): one wave per node ----------

template <int VEC>
__global__ void gather_csr_bf16(const short* __restrict__ h, short* __restrict__ agg,
                                const int* __restrict__ off, const int* __restrict__ csr,
                                int N) {
    typedef short svec __attribute__((ext_vector_type(VEC)));
    const int gw = (blockIdx.x * blockDim.x + threadIdx.x) >> 6;  // node id
    if (gw >= N) return;
    const int lane = threadIdx.x & 63;
    const int col = lane * VEC;
    const int F = 64 * VEC;
    const int base = off[gw];
    const int d = off[gw + 1] - base;

    float acc[VEC];
#pragma unroll
    for (int q = 0; q < VEC; ++q) acc[q] = 0.0f;

    int j = 0;
    for (; j + 4 <= d; j += 4) {
        int s0 = csr[base + j], s1 = csr[base + j + 1];
        int s2 = csr[base + j + 2], s3 = csr[base + j + 3];
        svec v0 = *reinterpret_cast<const svec*>(h + (size_t)s0 * F + col);
        svec v1 = *reinterpret_cast<const svec*>(h + (size_t)s1 * F + col);
        svec v2 = *reinterpret_cast<const svec*>(h + (size_t)s2 * F + col);
        svec v3 = *reinterpret_cast<const svec*>(h + (size_t)s3 * F + col);
#pragma unroll
        for (int q = 0; q < VEC; ++q)
            acc[q] += (bf2f(v0[q]) + bf2f(v1[q])) + (bf2f(v2[q]) + bf2f(v3[q]));
    }
    for (; j < d; ++j) {
        int s = csr[base + j];
        svec v = *reinterpret_cast<const svec*>(h + (size_t)s * F + col);
#pragma unroll
        for (int q = 0; q < VEC; ++q) acc[q] += bf2f(v[q]);
    }
    svec o;
#pragma unroll
    for (int q = 0; q < VEC; ++q) o[q] = f2bf(acc[q]);
    *reinterpret_cast<svec*>(agg + (size_t)gw * F + col) = o;
}

// ------- GEMM: C[M,256] = relu(A[M,K] @ W[K,256] + bias) -----------------
// 128x256 tile per block (full N), 512 threads, 8 waves (2x4), 16x16x32 MFMA.
// A read exactly once; Wt L2-resident.

template <typename OutT>
__launch_bounds__(512)
__global__ void gemm_bias_relu(const short* __restrict__ A, const short* __restrict__ Wt,
                               const float* __restrict__ bias, OutT* __restrict__ out,
                               int M, int K) {
    __shared__ short As[128][72];   // 18 KB (+8 pad)
    __shared__ short Bs[256][72];   // 36.9 KB

    const int tid = threadIdx.x;
    const int lane = tid & 63, wid = tid >> 6;
    const int wr = wid >> 2, wc = wid & 3;     // 2x4 waves -> 64x64 each
    const int lr = lane & 15, lg = lane >> 4;
    const int m0 = blockIdx.x * 128;

    f32x4 acc[4][4];
#pragma unroll
    for (int i = 0; i < 4; ++i)
#pragma unroll
        for (int j = 0; j < 4; ++j)
#pragma unroll
            for (int r = 0; r < 4; ++r) acc[i][j][r] = 0.0f;

    const int srA = tid >> 2;          // 0..127
    const int scA = (tid & 3) << 4;    // 0,16,32,48 shorts
    const int srB = tid >> 1;          // 0..255
    const int scB = (tid & 1) << 5;    // 0,32 shorts

    for (int k0 = 0; k0 < K; k0 += 64) {
        __syncthreads();
        {
            int gm = m0 + srA;
            if (gm < M) {
                const uint4* ap = reinterpret_cast<const uint4*>(A + (size_t)gm * K + k0 + scA);
                *reinterpret_cast<uint4*>(&As[srA][scA])     = ap[0];
                *reinterpret_cast<uint4*>(&As[srA][scA + 8]) = ap[1];
            } else {
                uint4 z = {0, 0, 0, 0};
                *reinterpret_cast<uint4*>(&As[srA][scA])     = z;
                *reinterpret_cast<uint4*>(&As[srA][scA + 8]) = z;
            }
            const uint4* bp = reinterpret_cast<const uint4*>(Wt + (size_t)srB * K + k0 + scB);
            *reinterpret_cast<uint4*>(&Bs[srB][scB])      = bp[0];
            *reinterpret_cast<uint4*>(&Bs[srB][scB + 8])  = bp[1];
            *reinterpret_cast<uint4*>(&Bs[srB][scB + 16]) = bp[2];
            *reinterpret_cast<uint4*>(&Bs[srB][scB + 24]) = bp[3];
        }
        __syncthreads();

#pragma unroll
        for (int ksub = 0; ksub < 2; ++ksub) {
            const int kb = ksub * 32 + 4 * lg;
            bf16x8 a[4], b[4];
#pragma unroll
            for (int mi = 0; mi < 4; ++mi) {
                int row = wr * 64 + mi * 16 + lr;
                uint2* pa = reinterpret_cast<uint2*>(&a[mi]);
                pa[0] = *reinterpret_cast<const uint2*>(&As[row][kb]);
                pa[1] = *reinterpret_cast<const uint2*>(&As[row][kb + 16]);
            }
#pragma unroll
            for (int ni = 0; ni < 4; ++ni) {
                int row = wc * 64 + ni * 16 + lr;
                uint2* pb = reinterpret_cast<uint2*>(&b[ni]);
                pb[0] = *reinterpret_cast<const uint2*>(&Bs[row][kb]);
                pb[1] = *reinterpret_cast<const uint2*>(&Bs[row][kb + 16]);
            }
#pragma unroll
            for (int mi = 0; mi < 4; ++mi)
#pragma unroll
                for (int ni = 0; ni < 4; ++ni)
                    acc[mi][ni] = __builtin_amdgcn_mfma_f32_16x16x32_bf16(a[mi], b[ni], acc[mi][ni], 0, 0, 0);
        }
    }

    float bv[4];
#pragma unroll
    for (int ni = 0; ni < 4; ++ni) bv[ni] = bias[wc * 64 + ni * 16 + lr];
#pragma unroll
    for (int mi = 0; mi < 4; ++mi) {
        int gmBase = m0 + wr * 64 + mi * 16 + 4 * lg;
#pragma unroll
        for (int r = 0; r < 4; ++r) {
            int gm = gmBase + r;
            if (gm >= M) continue;
#pragma unroll
            for (int ni = 0; ni < 4; ++ni) {
                int gn = wc * 64 + ni * 16 + lr;
                float v = acc[mi][ni][r] + bv[ni];
                v = v > 0.0f ? v : 0.0f;
                if constexpr (sizeof(OutT) == 2)
                    out[(size_t)gm * 256 + gn] = (OutT)f2bf(v);
                else
                    out[(size_t)gm * 256 + gn] = (OutT)v;
            }
        }
    }
}

extern "C" void kernel_launch(void* const* d_in, const int* in_sizes, int n_in,
                              void* d_out, int out_size, void* d_ws, size_t ws_size,
                              hipStream_t stream) {
    const float* x  = (const float*)d_in[0];
    const int*   ei = (const int*)d_in[1];
    const float* W1 = (const float*)d_in[2];
    const float* b1 = (const float*)d_in[3];
    const float* W2 = (const float*)d_in[4];
    const float* b2 = (const float*)d_in[5];
    const float* W3 = (const float*)d_in[6];
    const float* b3 = (const float*)d_in[7];
    float* out = (float*)d_out;
    short* hb  = (short*)d_out;  // inter-layer h (bf16) lives in d_out's space

    const int Nn = 50000, E = 800000, F0 = 128, F = 256;
    const int EB = (E + 4095) / 4096;      // edge-binning blocks

    short* aggb = (short*)d_ws;                 // 25.6 MB
    short* xb   = aggb + (size_t)Nn * F;        // 12.8 MB
    short* Wt1  = xb + (size_t)Nn * F0;
    short* Wt2  = Wt1 + F0 * F;
    short* Wt3  = Wt2 + F * F;
    int* off     = (int*)(Wt3 + F * F);         // Nn+1 ints
    int* cbin    = off + Nn + 1;                // NBIN
    int* cstart  = cbin + NBIN;                 // NBIN+1
    int* gcursor = cstart + NBIN + 1;           // NBIN
    unsigned* staging = (unsigned*)(gcursor + NBIN);  // 3.2 MB
    int* csr     = (int*)(staging + E);         // 3.2 MB

    // fused converts (weights transposed bf16, x bf16)
    prep<<<(163840 + 1600000 + 255) / 256, 256, 0, stream>>>(
        W1, W2, W3, (const float4*)x, Wt1, Wt2, Wt3, xb);

    // CSR build: coarse-bin -> fill -> finalize (local scans give global off)
    hipMemsetAsync(cbin, 0, NBIN * 4, stream);
    coarse_hist<<<EB, 256, 0, stream>>>(ei, cbin, E);
    coarse_scan<<<1, 128, 0, stream>>>(cbin, cstart, gcursor, off, E, Nn);
    bin_fill<<<EB, 256, 0, stream>>>(ei, gcursor, staging, E);
    bin_finalize<<<NBIN, 256, 0, stream>>>(staging, cstart, off, csr, Nn);

    const int gemmGrid = (Nn + 127) / 128;
    const int gatherBlocks = (Nn * 64 + 255) / 256;  // one wave per node

    // ---- layer 1 (F0=128: lane owns 2 bf16)
    gather_csr_bf16<2><<<gatherBlocks, 256, 0, stream>>>(xb, aggb, off, csr, Nn);
    gemm_bias_relu<short><<<gemmGrid, 512, 0, stream>>>(aggb, Wt1, b1, hb, Nn, F0);

    // ---- layer 2 (F=256: lane owns 4 bf16)
    gather_csr_bf16<4><<<gatherBlocks, 256, 0, stream>>>(hb, aggb, off, csr, Nn);
    gemm_bias_relu<short><<<gemmGrid, 512, 0, stream>>>(aggb, Wt2, b2, hb, Nn, F);

    // ---- layer 3 (final: f32 output)
    gather_csr_bf16<4><<<gatherBlocks, 256, 0, stream>>>(hb, aggb, off, csr, Nn);
    gemm_bias_relu<float><<<gemmGrid, 512, 0, stream>>>(aggb, Wt3, b3, out, Nn, F);
}

// Round 7
// 245.945 us; speedup vs baseline: 27.5871x; 1.0770x over previous
//
#include <hip/hip_runtime.h>
#include <hip/hip_bf16.h>

// 3-layer GCN: per layer  out = relu(segment_sum(h[src] -> dst) @ W + b)
// Aggregate-first + CSR gather. CSR built once via fixed-capacity binned
// counting sort; within each dst-bin, edges are LDS-sorted by src-bin so
// every node's edge list is ascending-source => gather's source working
// set is a sliding window (better L2 hit rate). Inter-layer tensors bf16;
// f32 accumulation in gather and MFMA.

#define NBIN 98      // ceil(50000/512) coarse dst bins
#define BINSH 9      // 512 nodes per bin
#define CAP 10240    // per-bin staging capacity (mean 8163, sigma ~90)

typedef short bf16x8 __attribute__((ext_vector_type(8)));
typedef float f32x4 __attribute__((ext_vector_type(4)));

__device__ __forceinline__ short f2bf(float f) {
    __hip_bfloat16 b = __float2bfloat16(f);
    return *reinterpret_cast<short*>(&b);
}
__device__ __forceinline__ float bf2f(short s) {
    union { unsigned u; float f; } c;
    c.u = ((unsigned)(unsigned short)s) << 16;
    return c.f;
}

// unpack uint4 (8 bf16) and accumulate into 8 f32
__device__ __forceinline__ void acc8(float* a, uint4 v) {
    unsigned w[4] = { v.x, v.y, v.z, v.w };
#pragma unroll
    for (int i = 0; i < 4; ++i) {
        union { unsigned u; float f; } lo, hi;
        lo.u = w[i] << 16;
        hi.u = w[i] & 0xFFFF0000u;
        a[2 * i]     += lo.f;
        a[2 * i + 1] += hi.f;
    }
}

// fused prep: W1,W2,W3 -> transposed bf16; x -> bf16
__global__ void prep(const float* __restrict__ W1, const float* __restrict__ W2,
                     const float* __restrict__ W3, const float4* __restrict__ x,
                     short* __restrict__ Wt1, short* __restrict__ Wt2,
                     short* __restrict__ Wt3, short* __restrict__ xb) {
    int idx = blockIdx.x * 256 + threadIdx.x;
    if (idx < 32768) {            // W1t [256][128]
        int n = idx >> 7, k = idx & 127;
        Wt1[idx] = f2bf(W1[k * 256 + n]);
    } else if (idx < 98304) {     // W2t [256][256]
        int i = idx - 32768, n = i >> 8, k = i & 255;
        Wt2[i] = f2bf(W2[k * 256 + n]);
    } else if (idx < 163840) {    // W3t [256][256]
        int i = idx - 98304, n = i >> 8, k = i & 255;
        Wt3[i] = f2bf(W3[k * 256 + n]);
    } else {                      // x: 1.6M float4 units
        int i = idx - 163840;
        if (i < 1600000) {
            float4 v = x[i];
            short tmp[4] = { f2bf(v.x), f2bf(v.y), f2bf(v.z), f2bf(v.w) };
            *reinterpret_cast<uint2*>(&xb[i * 4]) = *reinterpret_cast<uint2*>(tmp);
        }
    }
}

// ---------------- CSR build ----------------------------------------------

// append edges into fixed-capacity per-bin regions as (localdst<<16 | src)
__global__ void bin_fill(const int* __restrict__ ei, int* __restrict__ gcursor,
                         unsigned* __restrict__ staging, int E) {
    __shared__ int h[NBIN];
    __shared__ int cur[NBIN];
    for (int i = threadIdx.x; i < NBIN; i += 256) h[i] = 0;
    __syncthreads();
    int base = blockIdx.x * 4096;
    int d_[16], s_[16];
#pragma unroll
    for (int i = 0; i < 16; ++i) {
        int e = base + i * 256 + threadIdx.x;
        if (e < E) {
            s_[i] = ei[e];
            d_[i] = ei[E + e];
            atomicAdd(&h[d_[i] >> BINSH], 1);
        } else d_[i] = -1;
    }
    __syncthreads();
    for (int i = threadIdx.x; i < NBIN; i += 256)
        cur[i] = h[i] ? atomicAdd(&gcursor[i], h[i]) : 0;
    __syncthreads();
#pragma unroll
    for (int i = 0; i < 16; ++i) {
        if (d_[i] >= 0) {
            int bin = d_[i] >> BINSH;
            int p = atomicAdd(&cur[bin], 1);
            staging[(size_t)bin * CAP + p] =
                ((unsigned)(d_[i] & 511) << 16) | (unsigned)s_[i];
        }
    }
}

// exclusive scan of NBIN bin counts -> binbase; off[N] = E
__global__ void binbase_scan(const int* __restrict__ gcursor, int* __restrict__ binbase,
                             int* __restrict__ off, int E, int N) {
    __shared__ int lds[128];
    int t = threadIdx.x;
    int v = (t < NBIN) ? gcursor[t] : 0;
    lds[t] = v;
    __syncthreads();
    for (int d = 1; d < 128; d <<= 1) {
        int a = (t >= d) ? lds[t - d] : 0;
        __syncthreads();
        lds[t] += a;
        __syncthreads();
    }
    if (t < NBIN) binbase[t] = lds[t] - v;
    if (t == 0) off[N] = E;
}

// per dst-bin: count -> scans -> LDS sort by src-bin -> off + csr (src-ordered)
__launch_bounds__(256)
__global__ void bin_finalize(const unsigned* __restrict__ staging,
                             const int* __restrict__ cnt, const int* __restrict__ binbase,
                             int* __restrict__ off, int* __restrict__ csr, int N) {
    __shared__ unsigned sorted[CAP];   // 40 KB
    __shared__ int sb[128];            // src-bin counts -> cursors
    __shared__ int nd_c[512];
    __shared__ int nd_pos[512];
    __shared__ int psum[256];
    const int b = blockIdx.x, t = threadIdx.x;
    const int n = cnt[b];
    const unsigned* reg = staging + (size_t)b * CAP;
    const int gbase = binbase[b];

    if (t < 128) sb[t] = 0;
    nd_c[t] = 0; nd_c[t + 256] = 0;
    __syncthreads();
    for (int p = t; p < n; p += 256) {
        unsigned v = reg[p];
        atomicAdd(&sb[(v & 0xFFFFu) >> BINSH], 1);
        atomicAdd(&nd_c[v >> 16], 1);
    }
    __syncthreads();
    // exclusive scan of src-bin counts -> sb = cursor start within region
    int myc = (t < 128) ? sb[t] : 0;
    for (int d = 1; d < 128; d <<= 1) {
        int a = (t < 128 && t >= d) ? sb[t - d] : 0;
        __syncthreads();
        if (t < 128) sb[t] += a;
        __syncthreads();
    }
    if (t < 128) sb[t] -= myc;
    // node scan (512 via 2/thread) -> global csr positions + off
    int c0 = nd_c[2 * t], c1 = nd_c[2 * t + 1];
    psum[t] = c0 + c1;
    __syncthreads();
    for (int d = 1; d < 256; d <<= 1) {
        int a = (t >= d) ? psum[t - d] : 0;
        __syncthreads();
        psum[t] += a;
        __syncthreads();
    }
    int ebase = gbase + (t ? psum[t - 1] : 0);
    int nb0 = b << BINSH;
    nd_pos[2 * t]     = ebase;
    nd_pos[2 * t + 1] = ebase + c0;
    if (nb0 + 2 * t < N)     off[nb0 + 2 * t]     = ebase;
    if (nb0 + 2 * t + 1 < N) off[nb0 + 2 * t + 1] = ebase + c0;
    __syncthreads();
    // sort region by src-bin into LDS
    for (int p = t; p < n; p += 256) {
        unsigned v = reg[p];
        int pos = atomicAdd(&sb[(v & 0xFFFFu) >> BINSH], 1);
        sorted[pos] = v;
    }
    __syncthreads();
    // place in src-sorted order -> each node's list ascending in src(bin)
    for (int p = t; p < n; p += 256) {
        unsigned v = sorted[p];
        int pos = atomicAdd(&nd_pos[v >> 16], 1);
        csr[pos] = (int)(v & 0xFFFFu);
    }
}

// ------- gathers (bf16 in/out, f32 accum), one wave per node -------------

// F=256: 32 lanes x 16B cover a row; 2 edges per wave concurrently
__global__ void gather256(const short* __restrict__ h, short* __restrict__ agg,
                          const int* __restrict__ off, const int* __restrict__ csr,
                          int N) {
    const int gw = (blockIdx.x * blockDim.x + threadIdx.x) >> 6;
    if (gw >= N) return;
    const int lane = threadIdx.x & 63;
    const int half = lane >> 5, l = lane & 31;
    const int col = l * 8;
    const int base = off[gw];
    const int d = off[gw + 1] - base;

    float acc[8];
#pragma unroll
    for (int q = 0; q < 8; ++q) acc[q] = 0.0f;

    int j = 0;
    for (; j + 8 <= d; j += 8) {
        int s0 = csr[base + j + half];
        int s1 = csr[base + j + 2 + half];
        int s2 = csr[base + j + 4 + half];
        int s3 = csr[base + j + 6 + half];
        uint4 v0 = *reinterpret_cast<const uint4*>(h + (size_t)s0 * 256 + col);
        uint4 v1 = *reinterpret_cast<const uint4*>(h + (size_t)s1 * 256 + col);
        uint4 v2 = *reinterpret_cast<const uint4*>(h + (size_t)s2 * 256 + col);
        uint4 v3 = *reinterpret_cast<const uint4*>(h + (size_t)s3 * 256 + col);
        acc8(acc, v0); acc8(acc, v1); acc8(acc, v2); acc8(acc, v3);
    }
    for (; j + 2 <= d; j += 2) {
        int s = csr[base + j + half];
        uint4 v = *reinterpret_cast<const uint4*>(h + (size_t)s * 256 + col);
        acc8(acc, v);
    }
    if (j < d && half == 0) {   // odd tail: half 0 only
        int s = csr[base + j];
        uint4 v = *reinterpret_cast<const uint4*>(h + (size_t)s * 256 + col);
        acc8(acc, v);
    }
#pragma unroll
    for (int q = 0; q < 8; ++q) acc[q] += __shfl_xor(acc[q], 32);
    if (half == 0) {
        short o[8];
#pragma unroll
        for (int q = 0; q < 8; ++q) o[q] = f2bf(acc[q]);
        *reinterpret_cast<uint4*>(agg + (size_t)gw * 256 + col) =
            *reinterpret_cast<uint4*>(o);
    }
}

// F=128: 16 lanes x 16B cover a row; 4 edges per wave concurrently
__global__ void gather128(const short* __restrict__ h, short* __restrict__ agg,
                          const int* __restrict__ off, const int* __restrict__ csr,
                          int N) {
    const int gw = (blockIdx.x * blockDim.x + threadIdx.x) >> 6;
    if (gw >= N) return;
    const int lane = threadIdx.x & 63;
    const int q4 = lane >> 4, l = lane & 15;
    const int col = l * 8;
    const int base = off[gw];
    const int d = off[gw + 1] - base;

    float acc[8];
#pragma unroll
    for (int q = 0; q < 8; ++q) acc[q] = 0.0f;

    int j = 0;
    for (; j + 8 <= d; j += 8) {
        int s0 = csr[base + j + q4];
        int s1 = csr[base + j + 4 + q4];
        uint4 v0 = *reinterpret_cast<const uint4*>(h + (size_t)s0 * 128 + col);
        uint4 v1 = *reinterpret_cast<const uint4*>(h + (size_t)s1 * 128 + col);
        acc8(acc, v0); acc8(acc, v1);
    }
    for (; j + 4 <= d; j += 4) {
        int s = csr[base + j + q4];
        uint4 v = *reinterpret_cast<const uint4*>(h + (size_t)s * 128 + col);
        acc8(acc, v);
    }
    int rem = d - j;
    if (q4 < rem) {
        int s = csr[base + j + q4];
        uint4 v = *reinterpret_cast<const uint4*>(h + (size_t)s * 128 + col);
        acc8(acc, v);
    }
#pragma unroll
    for (int q = 0; q < 8; ++q) {
        acc[q] += __shfl_xor(acc[q], 32);
        acc[q] += __shfl_xor(acc[q], 16);
    }
    if (q4 == 0) {
        short o[8];
#pragma unroll
        for (int q = 0; q < 8; ++q) o[q] = f2bf(acc[q]);
        *reinterpret_cast<uint4*>(agg + (size_t)gw * 128 + col) =
            *reinterpret_cast<uint4*>(o);
    }
}

// ------- GEMM: C[M,256] = relu(A[M,K] @ W[K,256] + bias) -----------------
// 128x256 tile per block (full N), 512 threads, 8 waves (2x4), 16x16x32 MFMA.

template <typename OutT>
__launch_bounds__(512)
__global__ void gemm_bias_relu(const short* __restrict__ A, const short* __restrict__ Wt,
                               const float* __restrict__ bias, OutT* __restrict__ out,
                               int M, int K) {
    __shared__ short As[128][72];   // 18 KB (+8 pad)
    __shared__ short Bs[256][72];   // 36.9 KB

    const int tid = threadIdx.x;
    const int lane = tid & 63, wid = tid >> 6;
    const int wr = wid >> 2, wc = wid & 3;     // 2x4 waves -> 64x64 each
    const int lr = lane & 15, lg = lane >> 4;
    const int m0 = blockIdx.x * 128;

    f32x4 acc[4][4];
#pragma unroll
    for (int i = 0; i < 4; ++i)
#pragma unroll
        for (int j = 0; j < 4; ++j)
#pragma unroll
            for (int r = 0; r < 4; ++r) acc[i][j][r] = 0.0f;

    const int srA = tid >> 2;          // 0..127
    const int scA = (tid & 3) << 4;    // 0,16,32,48 shorts
    const int srB = tid >> 1;          // 0..255
    const int scB = (tid & 1) << 5;    // 0,32 shorts

    for (int k0 = 0; k0 < K; k0 += 64) {
        __syncthreads();
        {
            int gm = m0 + srA;
            if (gm < M) {
                const uint4* ap = reinterpret_cast<const uint4*>(A + (size_t)gm * K + k0 + scA);
                *reinterpret_cast<uint4*>(&As[srA][scA])     = ap[0];
                *reinterpret_cast<uint4*>(&As[srA][scA + 8]) = ap[1];
            } else {
                uint4 z = {0, 0, 0, 0};
                *reinterpret_cast<uint4*>(&As[srA][scA])     = z;
                *reinterpret_cast<uint4*>(&As[srA][scA + 8]) = z;
            }
            const uint4* bp = reinterpret_cast<const uint4*>(Wt + (size_t)srB * K + k0 + scB);
            *reinterpret_cast<uint4*>(&Bs[srB][scB])      = bp[0];
            *reinterpret_cast<uint4*>(&Bs[srB][scB + 8])  = bp[1];
            *reinterpret_cast<uint4*>(&Bs[srB][scB + 16]) = bp[2];
            *reinterpret_cast<uint4*>(&Bs[srB][scB + 24]) = bp[3];
        }
        __syncthreads();

#pragma unroll
        for (int ksub = 0; ksub < 2; ++ksub) {
            const int kb = ksub * 32 + 4 * lg;
            bf16x8 a[4], b[4];
#pragma unroll
            for (int mi = 0; mi < 4; ++mi) {
                int row = wr * 64 + mi * 16 + lr;
                uint2* pa = reinterpret_cast<uint2*>(&a[mi]);
                pa[0] = *reinterpret_cast<const uint2*>(&As[row][kb]);
                pa[1] = *reinterpret_cast<const uint2*>(&As[row][kb + 16]);
            }
#pragma unroll
            for (int ni = 0; ni < 4; ++ni) {
                int row = wc * 64 + ni * 16 + lr;
                uint2* pb = reinterpret_cast<uint2*>(&b[ni]);
                pb[0] = *reinterpret_cast<const uint2*>(&Bs[row][kb]);
                pb[1] = *reinterpret_cast<const uint2*>(&Bs[row][kb + 16]);
            }
#pragma unroll
            for (int mi = 0; mi < 4; ++mi)
#pragma unroll
                for (int ni = 0; ni < 4; ++ni)
                    acc[mi][ni] = __builtin_amdgcn_mfma_f32_16x16x32_bf16(a[mi], b[ni], acc[mi][ni], 0, 0, 0);
        }
    }

    float bv[4];
#pragma unroll
    for (int ni = 0; ni < 4; ++ni) bv[ni] = bias[wc * 64 + ni * 16 + lr];
#pragma unroll
    for (int mi = 0; mi < 4; ++mi) {
        int gmBase = m0 + wr * 64 + mi * 16 + 4 * lg;
#pragma unroll
        for (int r = 0; r < 4; ++r) {
            int gm = gmBase + r;
            if (gm >= M) continue;
#pragma unroll
            for (int ni = 0; ni < 4; ++ni) {
                int gn = wc * 64 + ni * 16 + lr;
                float v = acc[mi][ni][r] + bv[ni];
                v = v > 0.0f ? v : 0.0f;
                if constexpr (sizeof(OutT) == 2)
                    out[(size_t)gm * 256 + gn] = (OutT)f2bf(v);
                else
                    out[(size_t)gm * 256 + gn] = (OutT)v;
            }
        }
    }
}

extern "C" void kernel_launch(void* const* d_in, const int* in_sizes, int n_in,
                              void* d_out, int out_size, void* d_ws, size_t ws_size,
                              hipStream_t stream) {
    const float* x  = (const float*)d_in[0];
    const int*   ei = (const int*)d_in[1];
    const float* W1 = (const float*)d_in[2];
    const float* b1 = (const float*)d_in[3];
    const float* W2 = (const float*)d_in[4];
    const float* b2 = (const float*)d_in[5];
    const float* W3 = (const float*)d_in[6];
    const float* b3 = (const float*)d_in[7];
    float* out = (float*)d_out;
    short* hb  = (short*)d_out;  // inter-layer h (bf16) lives in d_out's space

    const int Nn = 50000, E = 800000, F0 = 128, F = 256;
    const int EB = (E + 4095) / 4096;      // edge-binning blocks

    short* aggb = (short*)d_ws;                 // 25.6 MB
    short* xb   = aggb + (size_t)Nn * F;        // 12.8 MB
    short* Wt1  = xb + (size_t)Nn * F0;
    short* Wt2  = Wt1 + F0 * F;
    short* Wt3  = Wt2 + F * F;
    int* off     = (int*)(Wt3 + F * F);         // Nn+1 ints
    int* gcursor = off + Nn + 1;                // NBIN
    int* binbase = gcursor + NBIN;              // NBIN
    unsigned* staging = (unsigned*)(binbase + NBIN);  // NBIN*CAP = 4.0 MB
    int* csr     = (int*)(staging + (size_t)NBIN * CAP);  // 3.2 MB

    // fused converts (weights transposed bf16, x bf16)
    prep<<<(163840 + 1600000 + 255) / 256, 256, 0, stream>>>(
        W1, W2, W3, (const float4*)x, Wt1, Wt2, Wt3, xb);

    // CSR build: fill fixed-cap bins -> bin bases -> finalize (src-sorted)
    hipMemsetAsync(gcursor, 0, NBIN * 4, stream);
    bin_fill<<<EB, 256, 0, stream>>>(ei, gcursor, staging, E);
    binbase_scan<<<1, 128, 0, stream>>>(gcursor, binbase, off, E, Nn);
    bin_finalize<<<NBIN, 256, 0, stream>>>(staging, gcursor, binbase, off, csr, Nn);

    const int gemmGrid = (Nn + 127) / 128;
    const int gatherBlocks = (Nn * 64 + 255) / 256;  // one wave per node

    // ---- layer 1
    gather128<<<gatherBlocks, 256, 0, stream>>>(xb, aggb, off, csr, Nn);
    gemm_bias_relu<short><<<gemmGrid, 512, 0, stream>>>(aggb, Wt1, b1, hb, Nn, F0);

    // ---- layer 2
    gather256<<<gatherBlocks, 256, 0, stream>>>(hb, aggb, off, csr, Nn);
    gemm_bias_relu<short><<<gemmGrid, 512, 0, stream>>>(aggb, Wt2, b2, hb, Nn, F);

    // ---- layer 3 (final: f32 output)
    gather256<<<gatherBlocks, 256, 0, stream>>>(hb, aggb, off, csr, Nn);
    gemm_bias_relu<float><<<gemmGrid, 512, 0, stream>>>(aggb, Wt3, b3, out, Nn, F);
}